// Round 6
// baseline (328.914 us; speedup 1.0000x reference)
//
#include <hip/hip_runtime.h>
#include <math.h>

static constexpr int K = 512;
static constexpr int D = 256;
static constexpr float ALPHA = 0.99f;
static constexpr float EPSF  = 2.2204460492503131e-16f;

typedef __bf16 bf16x8 __attribute__((ext_vector_type(8)));
typedef float floatx4 __attribute__((ext_vector_type(4)));
typedef unsigned long long u64;

__device__ __forceinline__ bf16x8 cvt8(const float4 a, const float4 b) {
  bf16x8 o;
  o[0] = (__bf16)a.x; o[1] = (__bf16)a.y; o[2] = (__bf16)a.z; o[3] = (__bf16)a.w;
  o[4] = (__bf16)b.x; o[5] = (__bf16)b.y; o[6] = (__bf16)b.z; o[7] = (__bf16)b.w;
  return o;
}

// ordered-float encoding: monotone map float -> u32 (for atomicMin argmin)
__device__ __forceinline__ unsigned int f2o(float f) {
  unsigned int u = __float_as_uint(f);
  return (u & 0x80000000u) ? ~u : (u | 0x80000000u);
}

// ====== anchors round 1: sim1 = F.q, fused grid-wide argmin (u64 atomicMin) ======
__global__ __launch_bounds__(256) void sim1_kernel(
    const float* __restrict__ F, const float* __restrict__ Q,
    float* __restrict__ simbuf, u64* __restrict__ m0)
{
  const int b = blockIdx.y;
  const int r0 = blockIdx.x * 64;
  const float* Fb = F + (size_t)b * (K * D);
  __shared__ __align__(16) float qs[D];
  const int t = threadIdx.x;
  const int wave = t >> 6, lane = t & 63;
  const int sub = lane >> 4, cg = lane & 15;
  qs[t] = Q[(size_t)b * D + t];
  __syncthreads();

  u64 best = ~0ULL;
  #pragma unroll
  for (int pass = 0; pass < 4; ++pass) {
    const int r = r0 + pass * 16 + wave * 4 + sub;
    const float* fr = Fb + (size_t)r * D;
    float p = 0.f;
    #pragma unroll
    for (int q = 0; q < 4; ++q) {
      const int c = q * 64 + cg * 4;
      const float4 fv = *(const float4*)(fr + c);
      const float4 qv = *(const float4*)(qs + c);
      p += fv.x*qv.x + fv.y*qv.y + fv.z*qv.z + fv.w*qv.w;
    }
    p += __shfl_xor(p, 1, 64); p += __shfl_xor(p, 2, 64);
    p += __shfl_xor(p, 4, 64); p += __shfl_xor(p, 8, 64);
    if (cg == 0) {
      simbuf[(size_t)b * K + r] = p;
      const u64 e = ((u64)f2o(p) << 32) | (unsigned int)r;
      best = (e < best) ? e : best;
    }
  }
  if (cg == 0) atomicMin(m0 + b, best);
}

// ====== anchors round 2: sim2 = F.f_a0, max with sim1, argmin ======
__global__ __launch_bounds__(256) void sim2_kernel(
    const float* __restrict__ F, const float* __restrict__ simbuf,
    const u64* __restrict__ m0, u64* __restrict__ m1)
{
  const int b = blockIdx.y;
  const int r0 = blockIdx.x * 64;
  const int a0 = (int)(m0[b] & 0xffffffffu);
  const float* Fb = F + (size_t)b * (K * D);
  __shared__ __align__(16) float qs[D];
  const int t = threadIdx.x;
  const int wave = t >> 6, lane = t & 63;
  const int sub = lane >> 4, cg = lane & 15;
  qs[t] = Fb[(size_t)a0 * D + t];
  __syncthreads();

  u64 best = ~0ULL;
  #pragma unroll
  for (int pass = 0; pass < 4; ++pass) {
    const int r = r0 + pass * 16 + wave * 4 + sub;
    const float* fr = Fb + (size_t)r * D;
    float p = 0.f;
    #pragma unroll
    for (int q = 0; q < 4; ++q) {
      const int c = q * 64 + cg * 4;
      const float4 fv = *(const float4*)(fr + c);
      const float4 qv = *(const float4*)(qs + c);
      p += fv.x*qv.x + fv.y*qv.y + fv.z*qv.z + fv.w*qv.w;
    }
    p += __shfl_xor(p, 1, 64); p += __shfl_xor(p, 2, 64);
    p += __shfl_xor(p, 4, 64); p += __shfl_xor(p, 8, 64);
    if (cg == 0) {
      const float m = fmaxf(simbuf[(size_t)b * K + r], p);
      const u64 e = ((u64)f2o(m) << 32) | (unsigned int)r;
      best = (e < best) ? e : best;
    }
  }
  if (cg == 0) atomicMin(m1 + b, best);
}

// ===== degrees: d[r] = sum_c!=r exp(f_r.f_c), virtual-W (no materialization) =====
__global__ __launch_bounds__(256) void deg_kernel(
    const float* __restrict__ F, float* __restrict__ Dg)
{
  const int b  = blockIdx.y;
  const int r0 = blockIdx.x * 128;
  const float* Fb = F + (size_t)b * (K * D);

  __shared__ __bf16 Asb[128][40];
  __shared__ __bf16 Bsb[128][40];
  const int t = threadIdx.x;
  const int wave = t >> 6, lane = t & 63;
  const int quad = lane >> 4, l15 = lane & 15;
  const int srow = t >> 1, skh = (t & 1) * 16;

  float rs[8] = {0.f};

  for (int cb = 0; cb < 4; ++cb) {
    floatx4 acc[2][8];
    #pragma unroll
    for (int i = 0; i < 2; ++i)
      #pragma unroll
      for (int j = 0; j < 8; ++j) acc[i][j] = (floatx4){0.f, 0.f, 0.f, 0.f};

    for (int kk = 0; kk < D; kk += 32) {
      __syncthreads();
      {
        const float* sa = Fb + (size_t)(r0 + srow) * D + kk + skh;
        *(bf16x8*)&Asb[srow][skh] =
            cvt8(*(const float4*)(sa + 0), *(const float4*)(sa + 4));
        *(bf16x8*)&Asb[srow][skh + 8] =
            cvt8(*(const float4*)(sa + 8), *(const float4*)(sa + 12));
        const float* sb = Fb + (size_t)(cb * 128 + srow) * D + kk + skh;
        *(bf16x8*)&Bsb[srow][skh] =
            cvt8(*(const float4*)(sb + 0), *(const float4*)(sb + 4));
        *(bf16x8*)&Bsb[srow][skh + 8] =
            cvt8(*(const float4*)(sb + 8), *(const float4*)(sb + 12));
      }
      __syncthreads();
      bf16x8 af[2], bf[8];
      #pragma unroll
      for (int tm = 0; tm < 2; ++tm)
        af[tm] = *(bf16x8*)&Asb[wave * 32 + tm * 16 + l15][quad * 8];
      #pragma unroll
      for (int tn = 0; tn < 8; ++tn)
        bf[tn] = *(bf16x8*)&Bsb[tn * 16 + l15][quad * 8];
      #pragma unroll
      for (int tm = 0; tm < 2; ++tm)
        #pragma unroll
        for (int tn = 0; tn < 8; ++tn)
          acc[tm][tn] = __builtin_amdgcn_mfma_f32_16x16x32_bf16(af[tm], bf[tn], acc[tm][tn], 0, 0, 0);
    }
    #pragma unroll
    for (int tm = 0; tm < 2; ++tm) {
      const int grb = r0 + wave * 32 + tm * 16 + quad * 4;
      #pragma unroll
      for (int tn = 0; tn < 8; ++tn) {
        const int gc = cb * 128 + tn * 16 + l15;
        #pragma unroll
        for (int r = 0; r < 4; ++r)
          rs[tm * 4 + r] += ((grb + r) == gc) ? 0.f : __expf(acc[tm][tn][r]);
      }
    }
  }
  #pragma unroll
  for (int s = 0; s < 8; ++s) {
    float v = rs[s];
    v += __shfl_xor(v, 1, 64); v += __shfl_xor(v, 2, 64);
    v += __shfl_xor(v, 4, 64); v += __shfl_xor(v, 8, 64);
    if (l15 == 0) {
      const int r = r0 + wave * 32 + (s >> 2) * 16 + quad * 4 + (s & 3);
      Dg[(size_t)b * K + r] = v;
    }
  }
}

// ===== first Neumann term: only 2 virtual-W columns needed (anchor cols) =====
__global__ __launch_bounds__(256) void iter0_kernel(
    const float* __restrict__ F, const float* __restrict__ Dg,
    const u64* __restrict__ m0, const u64* __restrict__ m1,
    float* __restrict__ u_out, float* __restrict__ z)
{
  const int b = blockIdx.y;
  const int r0 = blockIdx.x * 64;
  const int a0 = (int)(m0[b] & 0xffffffffu);
  const int a1 = (int)(m1[b] & 0xffffffffu);
  const float* Fb = F + (size_t)b * (K * D);
  __shared__ __align__(16) float qa[D], qb[D];
  __shared__ float dinv_s[K], sqd_s[K];
  __shared__ float red[4];
  const int t = threadIdx.x;
  const int wave = t >> 6, lane = t & 63;
  const int sub = lane >> 4, cg = lane & 15;

  qa[t] = Fb[(size_t)a0 * D + t];
  qb[t] = Fb[(size_t)a1 * D + t];
  float dsum = 0.f;
  for (int k = t; k < K; k += 256) {
    const float d = Dg[(size_t)b * K + k];
    dinv_s[k] = 1.0f / sqrtf(d + EPSF);
    sqd_s[k] = sqrtf(d);
    dsum += d;
  }
  #pragma unroll
  for (int off = 32; off >= 1; off >>= 1) dsum += __shfl_down(dsum, off, 64);
  if (lane == 0) red[wave] = dsum;
  __syncthreads();
  const float vn = 1.0f / sqrtf(red[0] + red[1] + red[2] + red[3]);
  const float s0 = vn * sqd_s[a0], s1 = vn * sqd_s[a1];
  const float dia0 = dinv_s[a0], dia1 = dinv_s[a1];

  float* uo0 = u_out + (size_t)b * 2 * K;
  float* uo1 = uo0 + K;
  float2* zb = (float2*)(z + (size_t)b * K * 2);

  #pragma unroll
  for (int pass = 0; pass < 4; ++pass) {
    const int r = r0 + pass * 16 + wave * 4 + sub;
    const float* fr = Fb + (size_t)r * D;
    float p0 = 0.f, p1 = 0.f;
    #pragma unroll
    for (int q = 0; q < 4; ++q) {
      const int c = q * 64 + cg * 4;
      const float4 fv = *(const float4*)(fr + c);
      const float4 av = *(const float4*)(qa + c);
      const float4 bv = *(const float4*)(qb + c);
      p0 += fv.x*av.x + fv.y*av.y + fv.z*av.z + fv.w*av.w;
      p1 += fv.x*bv.x + fv.y*bv.y + fv.z*bv.z + fv.w*bv.w;
    }
    p0 += __shfl_xor(p0, 1, 64); p0 += __shfl_xor(p0, 2, 64);
    p0 += __shfl_xor(p0, 4, 64); p0 += __shfl_xor(p0, 8, 64);
    p1 += __shfl_xor(p1, 1, 64); p1 += __shfl_xor(p1, 2, 64);
    p1 += __shfl_xor(p1, 4, 64); p1 += __shfl_xor(p1, 8, 64);
    if (cg == 0) {
      const float q0 = ((r == a0) ? 0.f : __expf(p0)) * dia0;
      const float q1 = ((r == a1) ? 0.f : __expf(p1)) * dia1;
      const float di = dinv_s[r];
      const float vr = vn * sqd_s[r];
      const float w0n = ALPHA * (di * q0 - vr * s0);
      const float w1n = ALPHA * (di * q1 - vr * s1);
      uo0[r] = w0n; uo1[r] = w1n;
      float2 zv;
      zv.x = ((r == a0) ? 1.f : 0.f) + w0n;
      zv.y = ((r == a1) ? 1.f : 0.f) + w1n;
      zb[r] = zv;
    }
  }
}

// ===== Neumann sweep on virtual W: w' = a(dinv o (W (dinv o w)) - v (v.w)) =====
// mode 1: u_out = w', z += w'.   mode 2: out = z + w' + a/(1-a) v v[anchor]
__global__ __launch_bounds__(256) void spmv_kernel(
    const float* __restrict__ F, const float* __restrict__ Dg,
    const u64* __restrict__ m0, const u64* __restrict__ m1,
    const float* __restrict__ u_in, float* __restrict__ u_out,
    float* __restrict__ z, float* __restrict__ out, const int mode)
{
  const int b  = blockIdx.y;
  const int r0 = blockIdx.x * 128;
  const float* Fb = F + (size_t)b * (K * D);

  __shared__ __bf16 Asb[128][40];
  __shared__ __bf16 Bsb[128][40];
  __shared__ __align__(16) float dinv_s[K], sqd_s[K], t0[K], t1[K];
  __shared__ float red[12];
  const int t = threadIdx.x;
  const int wave = t >> 6, lane = t & 63;
  const int quad = lane >> 4, l15 = lane & 15;
  const int srow = t >> 1, skh = (t & 1) * 16;
  const int a0 = (int)(m0[b] & 0xffffffffu);
  const int a1 = (int)(m1[b] & 0xffffffffu);

  const float* ui0 = u_in + (size_t)b * 2 * K;
  const float* ui1 = ui0 + K;
  float dsum = 0.f, p0 = 0.f, p1 = 0.f;
  for (int k = t; k < K; k += 256) {
    const float d = Dg[(size_t)b * K + k];
    const float sq = sqrtf(d);
    const float di = 1.0f / sqrtf(d + EPSF);
    dinv_s[k] = di; sqd_s[k] = sq; dsum += d;
    const float u0v = ui0[k], u1v = ui1[k];
    t0[k] = di * u0v; t1[k] = di * u1v;
    p0 += sq * u0v; p1 += sq * u1v;
  }
  #pragma unroll
  for (int off = 32; off >= 1; off >>= 1) {
    dsum += __shfl_down(dsum, off, 64);
    p0   += __shfl_down(p0,   off, 64);
    p1   += __shfl_down(p1,   off, 64);
  }
  if (lane == 0) { red[wave] = dsum; red[4 + wave] = p0; red[8 + wave] = p1; }
  __syncthreads();
  const float vn = 1.0f / sqrtf(red[0] + red[1] + red[2] + red[3]);
  const float s0 = vn * (red[4] + red[5] + red[6] + red[7]);
  const float s1 = vn * (red[8] + red[9] + red[10] + red[11]);

  float q0a[8] = {0.f}, q1a[8] = {0.f};

  for (int cb = 0; cb < 4; ++cb) {
    floatx4 acc[2][8];
    #pragma unroll
    for (int i = 0; i < 2; ++i)
      #pragma unroll
      for (int j = 0; j < 8; ++j) acc[i][j] = (floatx4){0.f, 0.f, 0.f, 0.f};

    for (int kk = 0; kk < D; kk += 32) {
      __syncthreads();
      {
        const float* sa = Fb + (size_t)(r0 + srow) * D + kk + skh;
        *(bf16x8*)&Asb[srow][skh] =
            cvt8(*(const float4*)(sa + 0), *(const float4*)(sa + 4));
        *(bf16x8*)&Asb[srow][skh + 8] =
            cvt8(*(const float4*)(sa + 8), *(const float4*)(sa + 12));
        const float* sb = Fb + (size_t)(cb * 128 + srow) * D + kk + skh;
        *(bf16x8*)&Bsb[srow][skh] =
            cvt8(*(const float4*)(sb + 0), *(const float4*)(sb + 4));
        *(bf16x8*)&Bsb[srow][skh + 8] =
            cvt8(*(const float4*)(sb + 8), *(const float4*)(sb + 12));
      }
      __syncthreads();
      bf16x8 af[2], bf[8];
      #pragma unroll
      for (int tm = 0; tm < 2; ++tm)
        af[tm] = *(bf16x8*)&Asb[wave * 32 + tm * 16 + l15][quad * 8];
      #pragma unroll
      for (int tn = 0; tn < 8; ++tn)
        bf[tn] = *(bf16x8*)&Bsb[tn * 16 + l15][quad * 8];
      #pragma unroll
      for (int tm = 0; tm < 2; ++tm)
        #pragma unroll
        for (int tn = 0; tn < 8; ++tn)
          acc[tm][tn] = __builtin_amdgcn_mfma_f32_16x16x32_bf16(af[tm], bf[tn], acc[tm][tn], 0, 0, 0);
    }

    // epilogue: exp + dot with t0/t1 (no W store)
    float t0c[8], t1c[8];
    #pragma unroll
    for (int tn = 0; tn < 8; ++tn) {
      t0c[tn] = t0[cb * 128 + tn * 16 + l15];
      t1c[tn] = t1[cb * 128 + tn * 16 + l15];
    }
    #pragma unroll
    for (int tm = 0; tm < 2; ++tm) {
      const int grb = r0 + wave * 32 + tm * 16 + quad * 4;
      #pragma unroll
      for (int tn = 0; tn < 8; ++tn) {
        const int gc = cb * 128 + tn * 16 + l15;
        #pragma unroll
        for (int r = 0; r < 4; ++r) {
          const float wv = ((grb + r) == gc) ? 0.f : __expf(acc[tm][tn][r]);
          q0a[tm * 4 + r] += wv * t0c[tn];
          q1a[tm * 4 + r] += wv * t1c[tn];
        }
      }
    }
  }

  float* uo0 = u_out + (size_t)b * 2 * K;
  float* uo1 = uo0 + K;
  float2* zb = (float2*)(z + (size_t)b * K * 2);
  float2* ob = (float2*)(out + (size_t)b * K * 2);
  const float c99 = ALPHA / (1.0f - ALPHA);
  const float cva0 = c99 * vn * sqd_s[a0];
  const float cva1 = c99 * vn * sqd_s[a1];

  #pragma unroll
  for (int s = 0; s < 8; ++s) {
    float q0 = q0a[s], q1 = q1a[s];
    q0 += __shfl_xor(q0, 1, 64); q0 += __shfl_xor(q0, 2, 64);
    q0 += __shfl_xor(q0, 4, 64); q0 += __shfl_xor(q0, 8, 64);
    q1 += __shfl_xor(q1, 1, 64); q1 += __shfl_xor(q1, 2, 64);
    q1 += __shfl_xor(q1, 4, 64); q1 += __shfl_xor(q1, 8, 64);
    if (l15 == 0) {
      const int r = r0 + wave * 32 + (s >> 2) * 16 + quad * 4 + (s & 3);
      const float di = dinv_s[r];
      const float vr = vn * sqd_s[r];
      const float w0n = ALPHA * (di * q0 - vr * s0);
      const float w1n = ALPHA * (di * q1 - vr * s1);
      if (mode == 1) {
        uo0[r] = w0n; uo1[r] = w1n;
        float2 zv = zb[r]; zv.x += w0n; zv.y += w1n; zb[r] = zv;
      } else {
        const float2 zv = zb[r];
        float2 o;
        o.x = zv.x + w0n + cva0 * vr;
        o.y = zv.y + w1n + cva1 * vr;
        ob[r] = o;
      }
    }
  }
}

// ==========================================================================
extern "C" void kernel_launch(void* const* d_in, const int* in_sizes, int n_in,
                              void* d_out, int out_size, void* d_ws, size_t ws_size,
                              hipStream_t stream) {
  const float* F = (const float*)d_in[0];   // [B,K,D]
  const float* Q = (const float*)d_in[1];   // [B,D]
  float* out = (float*)d_out;               // [B,K,2]
  const int B = in_sizes[1] / D;            // 128

  float* Dg   = (float*)d_ws;                            // B*K
  float* uA   = Dg + (size_t)B * K;                      // B*2*K
  float* uB   = uA + (size_t)B * 2 * K;                  // B*2*K
  float* zbuf = uB + (size_t)B * 2 * K;                  // B*K*2
  float* simb = zbuf + (size_t)B * K * 2;                // B*K
  u64*   m0   = (u64*)(simb + (size_t)B * K);            // B
  u64*   m1   = m0 + B;                                  // B

  hipMemsetAsync(m0, 0xFF, 2 * (size_t)B * sizeof(u64), stream);
  sim1_kernel<<<dim3(8, B), 256, 0, stream>>>(F, Q, simb, m0);
  sim2_kernel<<<dim3(8, B), 256, 0, stream>>>(F, simb, m0, m1);
  deg_kernel<<<dim3(4, B), 256, 0, stream>>>(F, Dg);
  iter0_kernel<<<dim3(8, B), 256, 0, stream>>>(F, Dg, m0, m1, uA, zbuf);
  spmv_kernel<<<dim3(4, B), 256, 0, stream>>>(F, Dg, m0, m1, uA, uB, zbuf, out, 1);
  spmv_kernel<<<dim3(4, B), 256, 0, stream>>>(F, Dg, m0, m1, uB, uA, zbuf, out, 2);
}

// Round 7
// 227.344 us; speedup vs baseline: 1.4468x; 1.4468x over previous
//
#include <hip/hip_runtime.h>
#include <math.h>

static constexpr int K = 512;
static constexpr int D = 256;
static constexpr float ALPHA = 0.99f;
static constexpr float EPSF  = 2.2204460492503131e-16f;

typedef __bf16 bf16x8 __attribute__((ext_vector_type(8)));
typedef float floatx4 __attribute__((ext_vector_type(4)));
typedef unsigned long long u64;

__device__ __forceinline__ bf16x8 cvt8(const float4 a, const float4 b) {
  bf16x8 o;
  o[0] = (__bf16)a.x; o[1] = (__bf16)a.y; o[2] = (__bf16)a.z; o[3] = (__bf16)a.w;
  o[4] = (__bf16)b.x; o[5] = (__bf16)b.y; o[6] = (__bf16)b.z; o[7] = (__bf16)b.w;
  return o;
}

// ordered-float encoding: monotone map float -> u32 (for atomicMin argmin)
__device__ __forceinline__ unsigned int f2o(float f) {
  unsigned int u = __float_as_uint(f);
  return (u & 0x80000000u) ? ~u : (u | 0x80000000u);
}

// ====== anchors round 1: sim1 = F.q, fused grid-wide argmin (u64 atomicMin) ======
__global__ __launch_bounds__(256) void sim1_kernel(
    const float* __restrict__ F, const float* __restrict__ Q,
    float* __restrict__ simbuf, u64* __restrict__ m0)
{
  const int b = blockIdx.y;
  const int r0 = blockIdx.x * 64;
  const float* Fb = F + (size_t)b * (K * D);
  __shared__ __align__(16) float qs[D];
  const int t = threadIdx.x;
  const int wave = t >> 6, lane = t & 63;
  const int sub = lane >> 4, cg = lane & 15;
  qs[t] = Q[(size_t)b * D + t];
  __syncthreads();

  u64 best = ~0ULL;
  #pragma unroll
  for (int pass = 0; pass < 4; ++pass) {
    const int r = r0 + pass * 16 + wave * 4 + sub;
    const float* fr = Fb + (size_t)r * D;
    float p = 0.f;
    #pragma unroll
    for (int q = 0; q < 4; ++q) {
      const int c = q * 64 + cg * 4;
      const float4 fv = *(const float4*)(fr + c);
      const float4 qv = *(const float4*)(qs + c);
      p += fv.x*qv.x + fv.y*qv.y + fv.z*qv.z + fv.w*qv.w;
    }
    p += __shfl_xor(p, 1, 64); p += __shfl_xor(p, 2, 64);
    p += __shfl_xor(p, 4, 64); p += __shfl_xor(p, 8, 64);
    if (cg == 0) {
      simbuf[(size_t)b * K + r] = p;
      const u64 e = ((u64)f2o(p) << 32) | (unsigned int)r;
      best = (e < best) ? e : best;
    }
  }
  if (cg == 0) atomicMin(m0 + b, best);
}

// ====== anchors round 2: sim2 = F.f_a0, max with sim1, argmin ======
__global__ __launch_bounds__(256) void sim2_kernel(
    const float* __restrict__ F, const float* __restrict__ simbuf,
    const u64* __restrict__ m0, u64* __restrict__ m1)
{
  const int b = blockIdx.y;
  const int r0 = blockIdx.x * 64;
  const int a0 = (int)(m0[b] & 0xffffffffu);
  const float* Fb = F + (size_t)b * (K * D);
  __shared__ __align__(16) float qs[D];
  const int t = threadIdx.x;
  const int wave = t >> 6, lane = t & 63;
  const int sub = lane >> 4, cg = lane & 15;
  qs[t] = Fb[(size_t)a0 * D + t];
  __syncthreads();

  u64 best = ~0ULL;
  #pragma unroll
  for (int pass = 0; pass < 4; ++pass) {
    const int r = r0 + pass * 16 + wave * 4 + sub;
    const float* fr = Fb + (size_t)r * D;
    float p = 0.f;
    #pragma unroll
    for (int q = 0; q < 4; ++q) {
      const int c = q * 64 + cg * 4;
      const float4 fv = *(const float4*)(fr + c);
      const float4 qv = *(const float4*)(qs + c);
      p += fv.x*qv.x + fv.y*qv.y + fv.z*qv.z + fv.w*qv.w;
    }
    p += __shfl_xor(p, 1, 64); p += __shfl_xor(p, 2, 64);
    p += __shfl_xor(p, 4, 64); p += __shfl_xor(p, 8, 64);
    if (cg == 0) {
      const float m = fmaxf(simbuf[(size_t)b * K + r], p);
      const u64 e = ((u64)f2o(m) << 32) | (unsigned int)r;
      best = (e < best) ? e : best;
    }
  }
  if (cg == 0) atomicMin(m1 + b, best);
}

// ===== gram: W = exp(F F^T) stored as bf16, zero diag; Dg = rowsum(stored W) =====
// grid (4, B): block computes a full 128-row strip (all 512 cols) -> direct Dg.
__global__ __launch_bounds__(256) void gram_kernel(
    const float* __restrict__ F, __bf16* __restrict__ W, float* __restrict__ Dg)
{
  const int b  = blockIdx.y;
  const int r0 = blockIdx.x * 128;
  const float* Fb = F + (size_t)b * (K * D);
  __bf16* Wb = W + (size_t)b * (K * K);

  __shared__ __bf16 Asb[128][40];
  __shared__ __bf16 Bsb[128][40];
  __shared__ __bf16 Cs[128][136];    // bf16 store staging (row stride 272 B)
  const int t = threadIdx.x;
  const int wave = t >> 6, lane = t & 63;
  const int quad = lane >> 4, l15 = lane & 15;
  const int srow = t >> 1, skh = (t & 1) * 16;

  float rs[8] = {0.f};

  for (int cb = 0; cb < 4; ++cb) {
    floatx4 acc[2][8];
    #pragma unroll
    for (int i = 0; i < 2; ++i)
      #pragma unroll
      for (int j = 0; j < 8; ++j) acc[i][j] = (floatx4){0.f, 0.f, 0.f, 0.f};

    for (int kk = 0; kk < D; kk += 32) {
      __syncthreads();
      {
        const float* sa = Fb + (size_t)(r0 + srow) * D + kk + skh;
        *(bf16x8*)&Asb[srow][skh] =
            cvt8(*(const float4*)(sa + 0), *(const float4*)(sa + 4));
        *(bf16x8*)&Asb[srow][skh + 8] =
            cvt8(*(const float4*)(sa + 8), *(const float4*)(sa + 12));
        const float* sb = Fb + (size_t)(cb * 128 + srow) * D + kk + skh;
        *(bf16x8*)&Bsb[srow][skh] =
            cvt8(*(const float4*)(sb + 0), *(const float4*)(sb + 4));
        *(bf16x8*)&Bsb[srow][skh + 8] =
            cvt8(*(const float4*)(sb + 8), *(const float4*)(sb + 12));
      }
      __syncthreads();
      bf16x8 af[2], bf[8];
      #pragma unroll
      for (int tm = 0; tm < 2; ++tm)
        af[tm] = *(bf16x8*)&Asb[wave * 32 + tm * 16 + l15][quad * 8];
      #pragma unroll
      for (int tn = 0; tn < 8; ++tn)
        bf[tn] = *(bf16x8*)&Bsb[tn * 16 + l15][quad * 8];
      #pragma unroll
      for (int tm = 0; tm < 2; ++tm)
        #pragma unroll
        for (int tn = 0; tn < 8; ++tn)
          acc[tm][tn] = __builtin_amdgcn_mfma_f32_16x16x32_bf16(af[tm], bf[tn], acc[tm][tn], 0, 0, 0);
    }

    // epilogue: exp, zero diag, round to bf16, stage, rowsum of ROUNDED values
    #pragma unroll
    for (int tm = 0; tm < 2; ++tm) {
      const int lr = wave * 32 + tm * 16 + quad * 4;
      #pragma unroll
      for (int tn = 0; tn < 8; ++tn) {
        const int gc = cb * 128 + tn * 16 + l15;
        #pragma unroll
        for (int r = 0; r < 4; ++r) {
          const float wv = ((r0 + lr + r) == gc) ? 0.f : __expf(acc[tm][tn][r]);
          const __bf16 wb16 = (__bf16)wv;
          Cs[lr + r][tn * 16 + l15] = wb16;
          rs[tm * 4 + r] += (float)wb16;
        }
      }
    }
    __syncthreads();
    // coalesced bf16 store: 2048 x 16B, 8 per thread
    #pragma unroll
    for (int i = 0; i < 8; ++i) {
      const int idx = t + i * 256;
      const int row = idx >> 4, c4 = idx & 15;
      *(uint4*)(Wb + (size_t)(r0 + row) * K + cb * 128 + c4 * 8) =
          *(const uint4*)&Cs[row][c4 * 8];
    }
  }

  #pragma unroll
  for (int s = 0; s < 8; ++s) {
    float v = rs[s];
    v += __shfl_xor(v, 1, 64); v += __shfl_xor(v, 2, 64);
    v += __shfl_xor(v, 4, 64); v += __shfl_xor(v, 8, 64);
    if (l15 == 0) {
      const int r = r0 + wave * 32 + (s >> 2) * 16 + quad * 4 + (s & 3);
      Dg[(size_t)b * K + r] = v;
    }
  }
}

// ===== first Neumann term: only 2 W-columns needed, recomputed from F =====
__global__ __launch_bounds__(256) void iter0_kernel(
    const float* __restrict__ F, const float* __restrict__ Dg,
    const u64* __restrict__ m0, const u64* __restrict__ m1,
    float* __restrict__ u_out, float* __restrict__ z)
{
  const int b = blockIdx.y;
  const int r0 = blockIdx.x * 64;
  const int a0 = (int)(m0[b] & 0xffffffffu);
  const int a1 = (int)(m1[b] & 0xffffffffu);
  const float* Fb = F + (size_t)b * (K * D);
  __shared__ __align__(16) float qa[D], qb[D];
  __shared__ float dinv_s[K], sqd_s[K];
  __shared__ float red[4];
  const int t = threadIdx.x;
  const int wave = t >> 6, lane = t & 63;
  const int sub = lane >> 4, cg = lane & 15;

  qa[t] = Fb[(size_t)a0 * D + t];
  qb[t] = Fb[(size_t)a1 * D + t];
  float dsum = 0.f;
  for (int k = t; k < K; k += 256) {
    const float d = Dg[(size_t)b * K + k];
    dinv_s[k] = 1.0f / sqrtf(d + EPSF);
    sqd_s[k] = sqrtf(d);
    dsum += d;
  }
  #pragma unroll
  for (int off = 32; off >= 1; off >>= 1) dsum += __shfl_down(dsum, off, 64);
  if (lane == 0) red[wave] = dsum;
  __syncthreads();
  const float vn = 1.0f / sqrtf(red[0] + red[1] + red[2] + red[3]);
  const float s0 = vn * sqd_s[a0], s1 = vn * sqd_s[a1];
  const float dia0 = dinv_s[a0], dia1 = dinv_s[a1];

  float* uo0 = u_out + (size_t)b * 2 * K;
  float* uo1 = uo0 + K;
  float2* zb = (float2*)(z + (size_t)b * K * 2);

  #pragma unroll
  for (int pass = 0; pass < 4; ++pass) {
    const int r = r0 + pass * 16 + wave * 4 + sub;
    const float* fr = Fb + (size_t)r * D;
    float p0 = 0.f, p1 = 0.f;
    #pragma unroll
    for (int q = 0; q < 4; ++q) {
      const int c = q * 64 + cg * 4;
      const float4 fv = *(const float4*)(fr + c);
      const float4 av = *(const float4*)(qa + c);
      const float4 bv = *(const float4*)(qb + c);
      p0 += fv.x*av.x + fv.y*av.y + fv.z*av.z + fv.w*av.w;
      p1 += fv.x*bv.x + fv.y*bv.y + fv.z*bv.z + fv.w*bv.w;
    }
    p0 += __shfl_xor(p0, 1, 64); p0 += __shfl_xor(p0, 2, 64);
    p0 += __shfl_xor(p0, 4, 64); p0 += __shfl_xor(p0, 8, 64);
    p1 += __shfl_xor(p1, 1, 64); p1 += __shfl_xor(p1, 2, 64);
    p1 += __shfl_xor(p1, 4, 64); p1 += __shfl_xor(p1, 8, 64);
    if (cg == 0) {
      const float q0 = ((r == a0) ? 0.f : __expf(p0)) * dia0;
      const float q1 = ((r == a1) ? 0.f : __expf(p1)) * dia1;
      const float di = dinv_s[r];
      const float vr = vn * sqd_s[r];
      const float w0n = ALPHA * (di * q0 - vr * s0);
      const float w1n = ALPHA * (di * q1 - vr * s1);
      uo0[r] = w0n; uo1[r] = w1n;
      float2 zv;
      zv.x = ((r == a0) ? 1.f : 0.f) + w0n;
      zv.y = ((r == a1) ? 1.f : 0.f) + w1n;
      zb[r] = zv;
    }
  }
}

// ===== Neumann sweep on stored bf16 W: w' = a(dinv o (W (dinv o w)) - v (v.w)) =====
// mode 1: u_out = w', z += w'.   mode 2: out = z + w' + a/(1-a) v v[anchor]
__global__ __launch_bounds__(256) void spmv_kernel(
    const __bf16* __restrict__ W, const float* __restrict__ Dg,
    const u64* __restrict__ m0, const u64* __restrict__ m1,
    const float* __restrict__ u_in, float* __restrict__ u_out,
    float* __restrict__ z, float* __restrict__ out, const int mode)
{
  const int b  = blockIdx.y;
  const int r0 = blockIdx.x * 128;
  const __bf16* Wb = W + (size_t)b * (K * K);
  __shared__ __align__(16) float dinv_s[K], sqd_s[K], t0[K], t1[K];
  __shared__ float red[12];
  const int t = threadIdx.x;
  const int wave = t >> 6, lane = t & 63;
  const int sub = lane >> 4, cg = lane & 15;
  const int a0 = (int)(m0[b] & 0xffffffffu);
  const int a1 = (int)(m1[b] & 0xffffffffu);

  const float* ui0 = u_in + (size_t)b * 2 * K;
  const float* ui1 = ui0 + K;
  float dsum = 0.f, p0 = 0.f, p1 = 0.f;
  for (int k = t; k < K; k += 256) {
    const float d = Dg[(size_t)b * K + k];
    const float sq = sqrtf(d);
    const float di = 1.0f / sqrtf(d + EPSF);
    dinv_s[k] = di; sqd_s[k] = sq; dsum += d;
    const float u0v = ui0[k], u1v = ui1[k];
    t0[k] = di * u0v; t1[k] = di * u1v;
    p0 += sq * u0v; p1 += sq * u1v;
  }
  #pragma unroll
  for (int off = 32; off >= 1; off >>= 1) {
    dsum += __shfl_down(dsum, off, 64);
    p0   += __shfl_down(p0,   off, 64);
    p1   += __shfl_down(p1,   off, 64);
  }
  if (lane == 0) { red[wave] = dsum; red[4 + wave] = p0; red[8 + wave] = p1; }
  __syncthreads();
  const float vn = 1.0f / sqrtf(red[0] + red[1] + red[2] + red[3]);
  const float s0 = vn * (red[4] + red[5] + red[6] + red[7]);
  const float s1 = vn * (red[8] + red[9] + red[10] + red[11]);

  float* uo0 = u_out + (size_t)b * 2 * K;
  float* uo1 = uo0 + K;
  float2* zb = (float2*)(z + (size_t)b * K * 2);
  float2* ob = (float2*)(out + (size_t)b * K * 2);
  const float c99 = ALPHA / (1.0f - ALPHA);
  const float cva0 = c99 * vn * sqd_s[a0];
  const float cva1 = c99 * vn * sqd_s[a1];

  #pragma unroll
  for (int pass = 0; pass < 8; ++pass) {
    const int r = r0 + wave * 32 + pass * 4 + sub;
    const __bf16* wrow = Wb + (size_t)r * K;
    float q0 = 0.f, q1 = 0.f;
    #pragma unroll
    for (int q = 0; q < 4; ++q) {
      const int c = q * 128 + cg * 8;
      const uint4 wv = *(const uint4*)(wrow + c);
      const float4 x0a = *(const float4*)(t0 + c);
      const float4 x0b = *(const float4*)(t0 + c + 4);
      const float4 x1a = *(const float4*)(t1 + c);
      const float4 x1b = *(const float4*)(t1 + c + 4);
      const float w0 = __uint_as_float(wv.x << 16);
      const float w1 = __uint_as_float(wv.x & 0xffff0000u);
      const float w2 = __uint_as_float(wv.y << 16);
      const float w3 = __uint_as_float(wv.y & 0xffff0000u);
      const float w4 = __uint_as_float(wv.z << 16);
      const float w5 = __uint_as_float(wv.z & 0xffff0000u);
      const float w6 = __uint_as_float(wv.w << 16);
      const float w7 = __uint_as_float(wv.w & 0xffff0000u);
      q0 += w0*x0a.x + w1*x0a.y + w2*x0a.z + w3*x0a.w
          + w4*x0b.x + w5*x0b.y + w6*x0b.z + w7*x0b.w;
      q1 += w0*x1a.x + w1*x1a.y + w2*x1a.z + w3*x1a.w
          + w4*x1b.x + w5*x1b.y + w6*x1b.z + w7*x1b.w;
    }
    q0 += __shfl_xor(q0, 1, 64); q0 += __shfl_xor(q0, 2, 64);
    q0 += __shfl_xor(q0, 4, 64); q0 += __shfl_xor(q0, 8, 64);
    q1 += __shfl_xor(q1, 1, 64); q1 += __shfl_xor(q1, 2, 64);
    q1 += __shfl_xor(q1, 4, 64); q1 += __shfl_xor(q1, 8, 64);
    if (cg == 0) {
      const float di = dinv_s[r];
      const float vr = vn * sqd_s[r];
      const float w0n = ALPHA * (di * q0 - vr * s0);
      const float w1n = ALPHA * (di * q1 - vr * s1);
      if (mode == 1) {
        uo0[r] = w0n; uo1[r] = w1n;
        float2 zv = zb[r]; zv.x += w0n; zv.y += w1n; zb[r] = zv;
      } else {
        const float2 zv = zb[r];
        float2 o;
        o.x = zv.x + w0n + cva0 * vr;
        o.y = zv.y + w1n + cva1 * vr;
        ob[r] = o;
      }
    }
  }
}

// ==========================================================================
extern "C" void kernel_launch(void* const* d_in, const int* in_sizes, int n_in,
                              void* d_out, int out_size, void* d_ws, size_t ws_size,
                              hipStream_t stream) {
  const float* F = (const float*)d_in[0];   // [B,K,D]
  const float* Q = (const float*)d_in[1];   // [B,D]
  float* out = (float*)d_out;               // [B,K,2]
  const int B = in_sizes[1] / D;            // 128

  __bf16* Wbuf = (__bf16*)d_ws;                          // B*K*K bf16 (67 MB)
  float* Dg   = (float*)(Wbuf + (size_t)B * K * K);      // B*K
  float* uA   = Dg + (size_t)B * K;                      // B*2*K
  float* uB   = uA + (size_t)B * 2 * K;                  // B*2*K
  float* zbuf = uB + (size_t)B * 2 * K;                  // B*K*2
  float* simb = zbuf + (size_t)B * K * 2;                // B*K
  u64*   m0   = (u64*)(simb + (size_t)B * K);            // B
  u64*   m1   = m0 + B;                                  // B

  hipMemsetAsync(m0, 0xFF, 2 * (size_t)B * sizeof(u64), stream);
  sim1_kernel<<<dim3(8, B), 256, 0, stream>>>(F, Q, simb, m0);
  sim2_kernel<<<dim3(8, B), 256, 0, stream>>>(F, simb, m0, m1);
  gram_kernel<<<dim3(4, B), 256, 0, stream>>>(F, Wbuf, Dg);
  iter0_kernel<<<dim3(8, B), 256, 0, stream>>>(F, Dg, m0, m1, uA, zbuf);
  spmv_kernel<<<dim3(4, B), 256, 0, stream>>>(Wbuf, Dg, m0, m1, uA, uB, zbuf, out, 1);
  spmv_kernel<<<dim3(4, B), 256, 0, stream>>>(Wbuf, Dg, m0, m1, uB, uA, zbuf, out, 2);
}

// Round 8
// 159.012 us; speedup vs baseline: 2.0685x; 1.4297x over previous
//
#include <hip/hip_runtime.h>
#include <math.h>

static constexpr int K = 512;
static constexpr int D = 256;
static constexpr float ALPHA = 0.99f;
static constexpr float EPSF  = 2.2204460492503131e-16f;

typedef __bf16 bf16x8 __attribute__((ext_vector_type(8)));
typedef __bf16 bf16x4 __attribute__((ext_vector_type(4)));
typedef float floatx4 __attribute__((ext_vector_type(4)));
typedef unsigned long long u64;

// ordered-float encoding: monotone map float -> u32 (for atomicMin argmin)
__device__ __forceinline__ unsigned int f2o(float f) {
  unsigned int u = __float_as_uint(f);
  return (u & 0x80000000u) ? ~u : (u | 0x80000000u);
}

// ====== anchors round 1: sim1 = F.q + argmin; ALSO emits bf16 copy of F ======
__global__ __launch_bounds__(256) void sim1_kernel(
    const float* __restrict__ F, const float* __restrict__ Q,
    __bf16* __restrict__ Fbf, float* __restrict__ simbuf, u64* __restrict__ m0)
{
  const int b = blockIdx.y;
  const int r0 = blockIdx.x * 64;
  const float* Fb = F + (size_t)b * (K * D);
  __bf16* Fbb = Fbf + (size_t)b * (K * D);
  __shared__ __align__(16) float qs[D];
  const int t = threadIdx.x;
  const int wave = t >> 6, lane = t & 63;
  const int sub = lane >> 4, cg = lane & 15;
  qs[t] = Q[(size_t)b * D + t];
  __syncthreads();

  u64 best = ~0ULL;
  #pragma unroll
  for (int pass = 0; pass < 4; ++pass) {
    const int r = r0 + pass * 16 + wave * 4 + sub;
    const float* fr = Fb + (size_t)r * D;
    float p = 0.f;
    #pragma unroll
    for (int q = 0; q < 4; ++q) {
      const int c = q * 64 + cg * 4;
      const float4 fv = *(const float4*)(fr + c);
      const float4 qv = *(const float4*)(qs + c);
      p += fv.x*qv.x + fv.y*qv.y + fv.z*qv.z + fv.w*qv.w;
      bf16x4 h;
      h[0] = (__bf16)fv.x; h[1] = (__bf16)fv.y;
      h[2] = (__bf16)fv.z; h[3] = (__bf16)fv.w;
      *(bf16x4*)(Fbb + (size_t)r * D + c) = h;
    }
    p += __shfl_xor(p, 1, 64); p += __shfl_xor(p, 2, 64);
    p += __shfl_xor(p, 4, 64); p += __shfl_xor(p, 8, 64);
    if (cg == 0) {
      simbuf[(size_t)b * K + r] = p;
      const u64 e = ((u64)f2o(p) << 32) | (unsigned int)r;
      best = (e < best) ? e : best;
    }
  }
  if (cg == 0) atomicMin(m0 + b, best);
}

// ====== anchors round 2: sim2 = F.f_a0, max with sim1, argmin (fp32-exact) ======
__global__ __launch_bounds__(256) void sim2_kernel(
    const float* __restrict__ F, const float* __restrict__ simbuf,
    const u64* __restrict__ m0, u64* __restrict__ m1)
{
  const int b = blockIdx.y;
  const int r0 = blockIdx.x * 64;
  const int a0 = (int)(m0[b] & 0xffffffffu);
  const float* Fb = F + (size_t)b * (K * D);
  __shared__ __align__(16) float qs[D];
  const int t = threadIdx.x;
  const int wave = t >> 6, lane = t & 63;
  const int sub = lane >> 4, cg = lane & 15;
  qs[t] = Fb[(size_t)a0 * D + t];
  __syncthreads();

  u64 best = ~0ULL;
  #pragma unroll
  for (int pass = 0; pass < 4; ++pass) {
    const int r = r0 + pass * 16 + wave * 4 + sub;
    const float* fr = Fb + (size_t)r * D;
    float p = 0.f;
    #pragma unroll
    for (int q = 0; q < 4; ++q) {
      const int c = q * 64 + cg * 4;
      const float4 fv = *(const float4*)(fr + c);
      const float4 qv = *(const float4*)(qs + c);
      p += fv.x*qv.x + fv.y*qv.y + fv.z*qv.z + fv.w*qv.w;
    }
    p += __shfl_xor(p, 1, 64); p += __shfl_xor(p, 2, 64);
    p += __shfl_xor(p, 4, 64); p += __shfl_xor(p, 8, 64);
    if (cg == 0) {
      const float m = fmaxf(simbuf[(size_t)b * K + r], p);
      const u64 e = ((u64)f2o(m) << 32) | (unsigned int)r;
      best = (e < best) ? e : best;
    }
  }
  if (cg == 0) atomicMin(m1 + b, best);
}

// ===== degrees: d[r] = sum_{c!=r} exp(f_r.f_c) via bf16 MFMA, no W store =====
// grid (B, 4): batch in x (128 % 8 == 0 -> all 4 strips of a batch on one XCD)
__global__ __launch_bounds__(256) void deg_kernel(
    const __bf16* __restrict__ Fbf, float* __restrict__ Dg)
{
  const int b  = blockIdx.x;
  const int r0 = blockIdx.y * 128;
  const __bf16* Fb = Fbf + (size_t)b * (K * D);

  __shared__ __bf16 Asb[128][40];
  __shared__ __bf16 Bsb[128][40];
  const int t = threadIdx.x;
  const int wave = t >> 6, lane = t & 63;
  const int quad = lane >> 4, l15 = lane & 15;
  const int srow = t >> 1, skh = (t & 1) * 16;

  float rs[8] = {0.f};

  for (int cb = 0; cb < 4; ++cb) {
    floatx4 acc[2][8];
    #pragma unroll
    for (int i = 0; i < 2; ++i)
      #pragma unroll
      for (int j = 0; j < 8; ++j) acc[i][j] = (floatx4){0.f, 0.f, 0.f, 0.f};

    for (int kk = 0; kk < D; kk += 32) {
      __syncthreads();
      {
        const __bf16* sa = Fb + (size_t)(r0 + srow) * D + kk + skh;
        *(uint4*)&Asb[srow][skh]     = *(const uint4*)(sa);
        *(uint4*)&Asb[srow][skh + 8] = *(const uint4*)(sa + 8);
        const __bf16* sb = Fb + (size_t)(cb * 128 + srow) * D + kk + skh;
        *(uint4*)&Bsb[srow][skh]     = *(const uint4*)(sb);
        *(uint4*)&Bsb[srow][skh + 8] = *(const uint4*)(sb + 8);
      }
      __syncthreads();
      bf16x8 af[2], bf[8];
      #pragma unroll
      for (int tm = 0; tm < 2; ++tm)
        af[tm] = *(bf16x8*)&Asb[wave * 32 + tm * 16 + l15][quad * 8];
      #pragma unroll
      for (int tn = 0; tn < 8; ++tn)
        bf[tn] = *(bf16x8*)&Bsb[tn * 16 + l15][quad * 8];
      #pragma unroll
      for (int tm = 0; tm < 2; ++tm)
        #pragma unroll
        for (int tn = 0; tn < 8; ++tn)
          acc[tm][tn] = __builtin_amdgcn_mfma_f32_16x16x32_bf16(af[tm], bf[tn], acc[tm][tn], 0, 0, 0);
    }
    #pragma unroll
    for (int tm = 0; tm < 2; ++tm) {
      const int grb = r0 + wave * 32 + tm * 16 + quad * 4;
      #pragma unroll
      for (int tn = 0; tn < 8; ++tn) {
        const int gc = cb * 128 + tn * 16 + l15;
        #pragma unroll
        for (int r = 0; r < 4; ++r)
          rs[tm * 4 + r] += ((grb + r) == gc) ? 0.f : __expf(acc[tm][tn][r]);
      }
    }
  }
  #pragma unroll
  for (int s = 0; s < 8; ++s) {
    float v = rs[s];
    v += __shfl_xor(v, 1, 64); v += __shfl_xor(v, 2, 64);
    v += __shfl_xor(v, 4, 64); v += __shfl_xor(v, 8, 64);
    if (l15 == 0) {
      const int r = r0 + wave * 32 + (s >> 2) * 16 + quad * 4 + (s & 3);
      Dg[(size_t)b * K + r] = v;
    }
  }
}

// ===== final: out = y + alpha*R*y + alpha/(1-alpha) * v * (v.y)  (NIT=1) =====
// alpha*R*y needs only the 2 anchor columns of W, computed fp32 from F.
__global__ __launch_bounds__(256) void final_kernel(
    const float* __restrict__ F, const float* __restrict__ Dg,
    const u64* __restrict__ m0, const u64* __restrict__ m1,
    float* __restrict__ out)
{
  const int b = blockIdx.y;
  const int r0 = blockIdx.x * 64;
  const int a0 = (int)(m0[b] & 0xffffffffu);
  const int a1 = (int)(m1[b] & 0xffffffffu);
  const float* Fb = F + (size_t)b * (K * D);
  __shared__ __align__(16) float qa[D], qb[D];
  __shared__ float dinv_s[K], sqd_s[K];
  __shared__ float red[4];
  const int t = threadIdx.x;
  const int wave = t >> 6, lane = t & 63;
  const int sub = lane >> 4, cg = lane & 15;

  qa[t] = Fb[(size_t)a0 * D + t];
  qb[t] = Fb[(size_t)a1 * D + t];
  float dsum = 0.f;
  for (int k = t; k < K; k += 256) {
    const float d = Dg[(size_t)b * K + k];
    dinv_s[k] = 1.0f / sqrtf(d + EPSF);
    sqd_s[k] = sqrtf(d);
    dsum += d;
  }
  #pragma unroll
  for (int off = 32; off >= 1; off >>= 1) dsum += __shfl_down(dsum, off, 64);
  if (lane == 0) red[wave] = dsum;
  __syncthreads();
  const float vn = 1.0f / sqrtf(red[0] + red[1] + red[2] + red[3]);
  const float s0 = vn * sqd_s[a0], s1 = vn * sqd_s[a1];   // v[a0], v[a1]
  const float dia0 = dinv_s[a0], dia1 = dinv_s[a1];
  const float c99 = ALPHA / (1.0f - ALPHA);

  float2* ob = (float2*)(out + (size_t)b * K * 2);

  #pragma unroll
  for (int pass = 0; pass < 4; ++pass) {
    const int r = r0 + pass * 16 + wave * 4 + sub;
    const float* fr = Fb + (size_t)r * D;
    float p0 = 0.f, p1 = 0.f;
    #pragma unroll
    for (int q = 0; q < 4; ++q) {
      const int c = q * 64 + cg * 4;
      const float4 fv = *(const float4*)(fr + c);
      const float4 av = *(const float4*)(qa + c);
      const float4 bv = *(const float4*)(qb + c);
      p0 += fv.x*av.x + fv.y*av.y + fv.z*av.z + fv.w*av.w;
      p1 += fv.x*bv.x + fv.y*bv.y + fv.z*bv.z + fv.w*bv.w;
    }
    p0 += __shfl_xor(p0, 1, 64); p0 += __shfl_xor(p0, 2, 64);
    p0 += __shfl_xor(p0, 4, 64); p0 += __shfl_xor(p0, 8, 64);
    p1 += __shfl_xor(p1, 1, 64); p1 += __shfl_xor(p1, 2, 64);
    p1 += __shfl_xor(p1, 4, 64); p1 += __shfl_xor(p1, 8, 64);
    if (cg == 0) {
      const float q0 = ((r == a0) ? 0.f : __expf(p0)) * dia0;
      const float q1 = ((r == a1) ? 0.f : __expf(p1)) * dia1;
      const float di = dinv_s[r];
      const float vr = vn * sqd_s[r];                      // v[r]
      const float w0n = ALPHA * (di * q0 - vr * s0);
      const float w1n = ALPHA * (di * q1 - vr * s1);
      float2 o;
      o.x = ((r == a0) ? 1.f : 0.f) + w0n + c99 * s0 * vr;
      o.y = ((r == a1) ? 1.f : 0.f) + w1n + c99 * s1 * vr;
      ob[r] = o;
    }
  }
}

// ==========================================================================
extern "C" void kernel_launch(void* const* d_in, const int* in_sizes, int n_in,
                              void* d_out, int out_size, void* d_ws, size_t ws_size,
                              hipStream_t stream) {
  const float* F = (const float*)d_in[0];   // [B,K,D]
  const float* Q = (const float*)d_in[1];   // [B,D]
  float* out = (float*)d_out;               // [B,K,2]
  const int B = in_sizes[1] / D;            // 128

  __bf16* Fbf = (__bf16*)d_ws;                           // B*K*D bf16 (33.5 MB)
  float* Dg   = (float*)(Fbf + (size_t)B * K * D);       // B*K
  float* simb = Dg + (size_t)B * K;                      // B*K
  u64*   m0   = (u64*)(simb + (size_t)B * K);            // B
  u64*   m1   = m0 + B;                                  // B

  hipMemsetAsync(m0, 0xFF, 2 * (size_t)B * sizeof(u64), stream);
  sim1_kernel<<<dim3(8, B), 256, 0, stream>>>(F, Q, Fbf, simb, m0);
  sim2_kernel<<<dim3(8, B), 256, 0, stream>>>(F, simb, m0, m1);
  deg_kernel<<<dim3(B, 4), 256, 0, stream>>>(Fbf, Dg);
  final_kernel<<<dim3(8, B), 256, 0, stream>>>(F, Dg, m0, m1, out);
}

// Round 9
// 151.023 us; speedup vs baseline: 2.1779x; 1.0529x over previous
//
#include <hip/hip_runtime.h>
#include <math.h>

static constexpr int K = 512;
static constexpr int D = 256;
static constexpr float ALPHA = 0.99f;
static constexpr float EPSF  = 2.2204460492503131e-16f;

typedef __bf16 bf16x8 __attribute__((ext_vector_type(8)));
typedef float floatx4 __attribute__((ext_vector_type(4)));
typedef unsigned long long u64;

// ordered-float encoding: monotone map float -> u32 (smaller float => smaller u32)
__device__ __forceinline__ unsigned int f2o(float f) {
  unsigned int u = __float_as_uint(f);
  return (u & 0x80000000u) ? ~u : (u | 0x80000000u);
}

__device__ __forceinline__ u64 umin64(u64 a, u64 b) { return a < b ? a : b; }

// ====== sim1: sim = F.q, per-block partial argmin; ALSO emits bf16 F ======
// grid (8, B): block covers 64 rows; partial best -> p0[b*8 + bx]
__global__ __launch_bounds__(256) void sim1_kernel(
    const float* __restrict__ F, const float* __restrict__ Q,
    __bf16* __restrict__ Fbf, float* __restrict__ simbuf, u64* __restrict__ p0)
{
  const int b = blockIdx.y;
  const int r0 = blockIdx.x * 64;
  const float* Fb = F + (size_t)b * (K * D);
  __bf16* Fbb = Fbf + (size_t)b * (K * D);
  __shared__ __align__(16) float qs[D];
  __shared__ u64 wred[4];
  const int t = threadIdx.x;
  const int wave = t >> 6, lane = t & 63;
  const int sub = lane >> 4, cg = lane & 15;
  qs[t] = Q[(size_t)b * D + t];
  __syncthreads();

  u64 best = ~0ULL;
  #pragma unroll
  for (int pass = 0; pass < 4; ++pass) {
    const int r = r0 + pass * 16 + wave * 4 + sub;
    const float* fr = Fb + (size_t)r * D;
    float p = 0.f;
    #pragma unroll
    for (int q = 0; q < 2; ++q) {
      const int c = q * 128 + cg * 8;
      const float4 f0 = *(const float4*)(fr + c);
      const float4 f1 = *(const float4*)(fr + c + 4);
      const float4 q0 = *(const float4*)(qs + c);
      const float4 q1 = *(const float4*)(qs + c + 4);
      p += f0.x*q0.x + f0.y*q0.y + f0.z*q0.z + f0.w*q0.w
         + f1.x*q1.x + f1.y*q1.y + f1.z*q1.z + f1.w*q1.w;
      bf16x8 h;
      h[0] = (__bf16)f0.x; h[1] = (__bf16)f0.y; h[2] = (__bf16)f0.z; h[3] = (__bf16)f0.w;
      h[4] = (__bf16)f1.x; h[5] = (__bf16)f1.y; h[6] = (__bf16)f1.z; h[7] = (__bf16)f1.w;
      *(bf16x8*)(Fbb + (size_t)r * D + c) = h;
    }
    p += __shfl_xor(p, 1, 64); p += __shfl_xor(p, 2, 64);
    p += __shfl_xor(p, 4, 64); p += __shfl_xor(p, 8, 64);
    if (cg == 0) {
      simbuf[(size_t)b * K + r] = p;
      best = umin64(best, ((u64)f2o(p) << 32) | (unsigned int)r);
    }
  }
  best = umin64(best, __shfl_xor(best, 16, 64));
  best = umin64(best, __shfl_xor(best, 32, 64));
  if (lane == 0) wred[wave] = best;
  __syncthreads();
  if (t == 0)
    p0[b * 8 + blockIdx.x] =
        umin64(umin64(wred[0], wred[1]), umin64(wred[2], wred[3]));
}

// ====== fused: blocks <512 do deg strips (bf16 MFMA), >=512 do sim2 ======
// deg: id = s*128 + b  -> id%8 == b%8 (XCD-local batches)
// sim2: id2 = s*128 + b, 128 rows each; partial best -> p1[b*4 + s]
__global__ __launch_bounds__(256) void fused_kernel(
    const float* __restrict__ F, const __bf16* __restrict__ Fbf,
    const float* __restrict__ simbuf, const u64* __restrict__ p0,
    u64* __restrict__ p1, float* __restrict__ Dg)
{
  __shared__ __align__(16) unsigned char smem[20480];
  const int id = blockIdx.x;
  const int t = threadIdx.x;
  const int wave = t >> 6, lane = t & 63;
  const int quad = lane >> 4, l15 = lane & 15;

  if (id < 512) {
    // ---------------- deg strip ----------------
    const int b = id & 127, strip = id >> 7;
    const int r0 = strip * 128;
    const __bf16* Fb = Fbf + (size_t)b * (K * D);
    __bf16 (*Asb)[40] = (__bf16(*)[40])smem;
    __bf16 (*Bsb)[40] = (__bf16(*)[40])(smem + 10240);
    const int srow = t >> 1, skh = (t & 1) * 16;

    float rs[8] = {0.f};
    for (int cb = 0; cb < 4; ++cb) {
      floatx4 acc[2][8];
      #pragma unroll
      for (int i = 0; i < 2; ++i)
        #pragma unroll
        for (int j = 0; j < 8; ++j) acc[i][j] = (floatx4){0.f, 0.f, 0.f, 0.f};

      for (int kk = 0; kk < D; kk += 32) {
        __syncthreads();
        {
          const __bf16* sa = Fb + (size_t)(r0 + srow) * D + kk + skh;
          *(uint4*)&Asb[srow][skh]     = *(const uint4*)(sa);
          *(uint4*)&Asb[srow][skh + 8] = *(const uint4*)(sa + 8);
          const __bf16* sb = Fb + (size_t)(cb * 128 + srow) * D + kk + skh;
          *(uint4*)&Bsb[srow][skh]     = *(const uint4*)(sb);
          *(uint4*)&Bsb[srow][skh + 8] = *(const uint4*)(sb + 8);
        }
        __syncthreads();
        bf16x8 af[2], bf[8];
        #pragma unroll
        for (int tm = 0; tm < 2; ++tm)
          af[tm] = *(bf16x8*)&Asb[wave * 32 + tm * 16 + l15][quad * 8];
        #pragma unroll
        for (int tn = 0; tn < 8; ++tn)
          bf[tn] = *(bf16x8*)&Bsb[tn * 16 + l15][quad * 8];
        #pragma unroll
        for (int tm = 0; tm < 2; ++tm)
          #pragma unroll
          for (int tn = 0; tn < 8; ++tn)
            acc[tm][tn] = __builtin_amdgcn_mfma_f32_16x16x32_bf16(af[tm], bf[tn], acc[tm][tn], 0, 0, 0);
      }
      #pragma unroll
      for (int tm = 0; tm < 2; ++tm) {
        const int grb = r0 + wave * 32 + tm * 16 + quad * 4;
        #pragma unroll
        for (int tn = 0; tn < 8; ++tn) {
          const int gc = cb * 128 + tn * 16 + l15;
          #pragma unroll
          for (int r = 0; r < 4; ++r)
            rs[tm * 4 + r] += ((grb + r) == gc) ? 0.f : __expf(acc[tm][tn][r]);
        }
      }
    }
    #pragma unroll
    for (int s = 0; s < 8; ++s) {
      float v = rs[s];
      v += __shfl_xor(v, 1, 64); v += __shfl_xor(v, 2, 64);
      v += __shfl_xor(v, 4, 64); v += __shfl_xor(v, 8, 64);
      if (l15 == 0) {
        const int r = r0 + wave * 32 + (s >> 2) * 16 + quad * 4 + (s & 3);
        Dg[(size_t)b * K + r] = v;
      }
    }
  } else {
    // ---------------- sim2 quarter ----------------
    const int id2 = id - 512;
    const int b = id2 & 127, s = id2 >> 7;
    const int r0 = s * 128;
    const float* Fb = F + (size_t)b * (K * D);
    float* qs = (float*)smem;
    u64* wred = (u64*)(smem + 1024);
    const int sub = lane >> 4, cg = lane & 15;

    u64 e0 = p0[b * 8];
    #pragma unroll
    for (int i = 1; i < 8; ++i) e0 = umin64(e0, p0[b * 8 + i]);
    const int a0 = (int)(e0 & 0xffffffffu);

    qs[t] = Fb[(size_t)a0 * D + t];
    __syncthreads();

    u64 best = ~0ULL;
    #pragma unroll
    for (int pass = 0; pass < 8; ++pass) {
      const int r = r0 + pass * 16 + wave * 4 + sub;
      const float* fr = Fb + (size_t)r * D;
      float p = 0.f;
      #pragma unroll
      for (int q = 0; q < 2; ++q) {
        const int c = q * 128 + cg * 8;
        const float4 f0 = *(const float4*)(fr + c);
        const float4 f1 = *(const float4*)(fr + c + 4);
        const float4 q0 = *(const float4*)(qs + c);
        const float4 q1 = *(const float4*)(qs + c + 4);
        p += f0.x*q0.x + f0.y*q0.y + f0.z*q0.z + f0.w*q0.w
           + f1.x*q1.x + f1.y*q1.y + f1.z*q1.z + f1.w*q1.w;
      }
      p += __shfl_xor(p, 1, 64); p += __shfl_xor(p, 2, 64);
      p += __shfl_xor(p, 4, 64); p += __shfl_xor(p, 8, 64);
      if (cg == 0) {
        const float m = fmaxf(simbuf[(size_t)b * K + r], p);
        best = umin64(best, ((u64)f2o(m) << 32) | (unsigned int)r);
      }
    }
    best = umin64(best, __shfl_xor(best, 16, 64));
    best = umin64(best, __shfl_xor(best, 32, 64));
    if (lane == 0) wred[wave] = best;
    __syncthreads();
    if (t == 0)
      p1[b * 4 + s] =
          umin64(umin64(wred[0], wred[1]), umin64(wred[2], wred[3]));
  }
}

// ===== final: out = y + alpha*R*y + alpha/(1-alpha) * v * (v.y)  (NIT=1) =====
// grid (4, B): 128 rows/block. Reduces p0/p1 to anchors in-block.
__global__ __launch_bounds__(256) void final_kernel(
    const float* __restrict__ F, const float* __restrict__ Dg,
    const u64* __restrict__ p0, const u64* __restrict__ p1,
    float* __restrict__ out)
{
  const int b = blockIdx.y;
  const int r0 = blockIdx.x * 128;
  const float* Fb = F + (size_t)b * (K * D);
  __shared__ __align__(16) float qa[D], qb[D];
  __shared__ float dinv_s[K], sqd_s[K];
  __shared__ float red[4];
  const int t = threadIdx.x;
  const int wave = t >> 6, lane = t & 63;
  const int sub = lane >> 4, cg = lane & 15;

  u64 e0 = p0[b * 8];
  #pragma unroll
  for (int i = 1; i < 8; ++i) e0 = umin64(e0, p0[b * 8 + i]);
  u64 e1 = p1[b * 4];
  #pragma unroll
  for (int i = 1; i < 4; ++i) e1 = umin64(e1, p1[b * 4 + i]);
  const int a0 = (int)(e0 & 0xffffffffu);
  const int a1 = (int)(e1 & 0xffffffffu);

  qa[t] = Fb[(size_t)a0 * D + t];
  qb[t] = Fb[(size_t)a1 * D + t];
  float dsum = 0.f;
  for (int k = t; k < K; k += 256) {
    const float d = Dg[(size_t)b * K + k];
    dinv_s[k] = 1.0f / sqrtf(d + EPSF);
    sqd_s[k] = sqrtf(d);
    dsum += d;
  }
  #pragma unroll
  for (int off = 32; off >= 1; off >>= 1) dsum += __shfl_down(dsum, off, 64);
  if (lane == 0) red[wave] = dsum;
  __syncthreads();
  const float vn = 1.0f / sqrtf(red[0] + red[1] + red[2] + red[3]);
  const float s0 = vn * sqd_s[a0], s1 = vn * sqd_s[a1];   // v[a0], v[a1]
  const float dia0 = dinv_s[a0], dia1 = dinv_s[a1];
  const float c99 = ALPHA / (1.0f - ALPHA);

  float2* ob = (float2*)(out + (size_t)b * K * 2);

  #pragma unroll
  for (int pass = 0; pass < 8; ++pass) {
    const int r = r0 + pass * 16 + wave * 4 + sub;
    const float* fr = Fb + (size_t)r * D;
    float pa = 0.f, pb = 0.f;
    #pragma unroll
    for (int q = 0; q < 2; ++q) {
      const int c = q * 128 + cg * 8;
      const float4 f0 = *(const float4*)(fr + c);
      const float4 f1 = *(const float4*)(fr + c + 4);
      const float4 a0v = *(const float4*)(qa + c);
      const float4 a1v = *(const float4*)(qa + c + 4);
      const float4 b0v = *(const float4*)(qb + c);
      const float4 b1v = *(const float4*)(qb + c + 4);
      pa += f0.x*a0v.x + f0.y*a0v.y + f0.z*a0v.z + f0.w*a0v.w
          + f1.x*a1v.x + f1.y*a1v.y + f1.z*a1v.z + f1.w*a1v.w;
      pb += f0.x*b0v.x + f0.y*b0v.y + f0.z*b0v.z + f0.w*b0v.w
          + f1.x*b1v.x + f1.y*b1v.y + f1.z*b1v.z + f1.w*b1v.w;
    }
    pa += __shfl_xor(pa, 1, 64); pa += __shfl_xor(pa, 2, 64);
    pa += __shfl_xor(pa, 4, 64); pa += __shfl_xor(pa, 8, 64);
    pb += __shfl_xor(pb, 1, 64); pb += __shfl_xor(pb, 2, 64);
    pb += __shfl_xor(pb, 4, 64); pb += __shfl_xor(pb, 8, 64);
    if (cg == 0) {
      const float q0 = ((r == a0) ? 0.f : __expf(pa)) * dia0;
      const float q1 = ((r == a1) ? 0.f : __expf(pb)) * dia1;
      const float di = dinv_s[r];
      const float vr = vn * sqd_s[r];                      // v[r]
      const float w0n = ALPHA * (di * q0 - vr * s0);
      const float w1n = ALPHA * (di * q1 - vr * s1);
      float2 o;
      o.x = ((r == a0) ? 1.f : 0.f) + w0n + c99 * s0 * vr;
      o.y = ((r == a1) ? 1.f : 0.f) + w1n + c99 * s1 * vr;
      ob[r] = o;
    }
  }
}

// ==========================================================================
extern "C" void kernel_launch(void* const* d_in, const int* in_sizes, int n_in,
                              void* d_out, int out_size, void* d_ws, size_t ws_size,
                              hipStream_t stream) {
  const float* F = (const float*)d_in[0];   // [B,K,D]
  const float* Q = (const float*)d_in[1];   // [B,D]
  float* out = (float*)d_out;               // [B,K,2]
  const int B = in_sizes[1] / D;            // 128

  __bf16* Fbf = (__bf16*)d_ws;                           // B*K*D bf16 (33.5 MB)
  float* Dg   = (float*)(Fbf + (size_t)B * K * D);       // B*K
  float* simb = Dg + (size_t)B * K;                      // B*K
  u64*   p0   = (u64*)(simb + (size_t)B * K);            // B*8
  u64*   p1   = p0 + (size_t)B * 8;                      // B*4

  sim1_kernel<<<dim3(8, B), 256, 0, stream>>>(F, Q, Fbf, simb, p0);
  fused_kernel<<<1024, 256, 0, stream>>>(F, Fbf, simb, p0, p1, Dg);
  final_kernel<<<dim3(4, B), 256, 0, stream>>>(F, Dg, p0, p1, out);
}

// Round 10
// 146.027 us; speedup vs baseline: 2.2524x; 1.0342x over previous
//
#include <hip/hip_runtime.h>
#include <math.h>

static constexpr int K = 512;
static constexpr int D = 256;
static constexpr float ALPHA = 0.99f;
static constexpr float EPSF  = 2.2204460492503131e-16f;

typedef __bf16 bf16x8 __attribute__((ext_vector_type(8)));
typedef float floatx4 __attribute__((ext_vector_type(4)));
typedef unsigned long long u64;

// ordered-float encoding: monotone map float -> u32 (smaller float => smaller u32)
__device__ __forceinline__ unsigned int f2o(float f) {
  unsigned int u = __float_as_uint(f);
  return (u & 0x80000000u) ? ~u : (u | 0x80000000u);
}

__device__ __forceinline__ u64 umin64(u64 a, u64 b) { return a < b ? a : b; }

// ====== sim1: sim = F.q, per-block partial argmin; ALSO emits bf16 F ======
// grid (8, B): block covers 64 rows; partial best -> p0[b*8 + bx]
__global__ __launch_bounds__(256) void sim1_kernel(
    const float* __restrict__ F, const float* __restrict__ Q,
    __bf16* __restrict__ Fbf, float* __restrict__ simbuf, u64* __restrict__ p0)
{
  const int b = blockIdx.y;
  const int r0 = blockIdx.x * 64;
  const float* Fb = F + (size_t)b * (K * D);
  __bf16* Fbb = Fbf + (size_t)b * (K * D);
  __shared__ __align__(16) float qs[D];
  __shared__ u64 wred[4];
  const int t = threadIdx.x;
  const int wave = t >> 6, lane = t & 63;
  const int sub = lane >> 4, cg = lane & 15;
  qs[t] = Q[(size_t)b * D + t];
  __syncthreads();

  u64 best = ~0ULL;
  #pragma unroll
  for (int pass = 0; pass < 4; ++pass) {
    const int r = r0 + pass * 16 + wave * 4 + sub;
    const float* fr = Fb + (size_t)r * D;
    float p = 0.f;
    #pragma unroll
    for (int q = 0; q < 2; ++q) {
      const int c = q * 128 + cg * 8;
      const float4 f0 = *(const float4*)(fr + c);
      const float4 f1 = *(const float4*)(fr + c + 4);
      const float4 q0 = *(const float4*)(qs + c);
      const float4 q1 = *(const float4*)(qs + c + 4);
      p += f0.x*q0.x + f0.y*q0.y + f0.z*q0.z + f0.w*q0.w
         + f1.x*q1.x + f1.y*q1.y + f1.z*q1.z + f1.w*q1.w;
      bf16x8 h;
      h[0] = (__bf16)f0.x; h[1] = (__bf16)f0.y; h[2] = (__bf16)f0.z; h[3] = (__bf16)f0.w;
      h[4] = (__bf16)f1.x; h[5] = (__bf16)f1.y; h[6] = (__bf16)f1.z; h[7] = (__bf16)f1.w;
      *(bf16x8*)(Fbb + (size_t)r * D + c) = h;
    }
    p += __shfl_xor(p, 1, 64); p += __shfl_xor(p, 2, 64);
    p += __shfl_xor(p, 4, 64); p += __shfl_xor(p, 8, 64);
    if (cg == 0) {
      simbuf[(size_t)b * K + r] = p;
      best = umin64(best, ((u64)f2o(p) << 32) | (unsigned int)r);
    }
  }
  best = umin64(best, __shfl_xor(best, 16, 64));
  best = umin64(best, __shfl_xor(best, 32, 64));
  if (lane == 0) wred[wave] = best;
  __syncthreads();
  if (t == 0)
    p0[b * 8 + blockIdx.x] =
        umin64(umin64(wred[0], wred[1]), umin64(wred[2], wred[3]));
}

// ====== fused: blocks <1024 = deg half-strips (bf16 MFMA); >=1024 = sim2 ======
// deg id = (strip*2+half)*128 + b  -> id%8 == b%8 (XCD-local batches)
// writes partial degrees Dgp[half][b][r]; final sums the two halves.
__global__ __launch_bounds__(256) void fused_kernel(
    const float* __restrict__ F, const __bf16* __restrict__ Fbf,
    const float* __restrict__ simbuf, const u64* __restrict__ p0,
    u64* __restrict__ p1, float* __restrict__ Dgp)
{
  __shared__ __align__(16) unsigned char smem[36864];
  const int id = blockIdx.x;
  const int t = threadIdx.x;
  const int wave = t >> 6, lane = t & 63;
  const int quad = lane >> 4, l15 = lane & 15;

  if (id < 1024) {
    // ---------------- deg half-strip: 128 rows x 256 cols ----------------
    const int b = id & 127;
    const int sid = id >> 7;                 // 0..7
    const int strip = sid >> 1, half = sid & 1;
    const int r0 = strip * 128;
    const __bf16* Fb = Fbf + (size_t)b * (K * D);
    __bf16 (*Asb)[72] = (__bf16(*)[72])smem;            // 128 x 72 bf16
    __bf16 (*Bsb)[72] = (__bf16(*)[72])(smem + 18432);
    const int srow = t >> 1, skh = (t & 1) * 32;

    float rs[8] = {0.f};
    for (int cb = half * 2; cb < half * 2 + 2; ++cb) {
      floatx4 acc[2][8];
      #pragma unroll
      for (int i = 0; i < 2; ++i)
        #pragma unroll
        for (int j = 0; j < 8; ++j) acc[i][j] = (floatx4){0.f, 0.f, 0.f, 0.f};

      for (int kk = 0; kk < D; kk += 64) {
        __syncthreads();
        {
          const __bf16* sa = Fb + (size_t)(r0 + srow) * D + kk + skh;
          *(uint4*)&Asb[srow][skh +  0] = *(const uint4*)(sa +  0);
          *(uint4*)&Asb[srow][skh +  8] = *(const uint4*)(sa +  8);
          *(uint4*)&Asb[srow][skh + 16] = *(const uint4*)(sa + 16);
          *(uint4*)&Asb[srow][skh + 24] = *(const uint4*)(sa + 24);
          const __bf16* sb = Fb + (size_t)(cb * 128 + srow) * D + kk + skh;
          *(uint4*)&Bsb[srow][skh +  0] = *(const uint4*)(sb +  0);
          *(uint4*)&Bsb[srow][skh +  8] = *(const uint4*)(sb +  8);
          *(uint4*)&Bsb[srow][skh + 16] = *(const uint4*)(sb + 16);
          *(uint4*)&Bsb[srow][skh + 24] = *(const uint4*)(sb + 24);
        }
        __syncthreads();
        #pragma unroll
        for (int k2 = 0; k2 < 64; k2 += 32) {
          bf16x8 af[2], bf[8];
          #pragma unroll
          for (int tm = 0; tm < 2; ++tm)
            af[tm] = *(bf16x8*)&Asb[wave * 32 + tm * 16 + l15][k2 + quad * 8];
          #pragma unroll
          for (int tn = 0; tn < 8; ++tn)
            bf[tn] = *(bf16x8*)&Bsb[tn * 16 + l15][k2 + quad * 8];
          #pragma unroll
          for (int tm = 0; tm < 2; ++tm)
            #pragma unroll
            for (int tn = 0; tn < 8; ++tn)
              acc[tm][tn] = __builtin_amdgcn_mfma_f32_16x16x32_bf16(af[tm], bf[tn], acc[tm][tn], 0, 0, 0);
        }
      }
      #pragma unroll
      for (int tm = 0; tm < 2; ++tm) {
        const int grb = r0 + wave * 32 + tm * 16 + quad * 4;
        #pragma unroll
        for (int tn = 0; tn < 8; ++tn) {
          const int gc = cb * 128 + tn * 16 + l15;
          #pragma unroll
          for (int r = 0; r < 4; ++r)
            rs[tm * 4 + r] += ((grb + r) == gc) ? 0.f : __expf(acc[tm][tn][r]);
        }
      }
    }
    #pragma unroll
    for (int s = 0; s < 8; ++s) {
      float v = rs[s];
      v += __shfl_xor(v, 1, 64); v += __shfl_xor(v, 2, 64);
      v += __shfl_xor(v, 4, 64); v += __shfl_xor(v, 8, 64);
      if (l15 == 0) {
        const int r = r0 + wave * 32 + (s >> 2) * 16 + quad * 4 + (s & 3);
        Dgp[(size_t)half * (128 * K) + (size_t)b * K + r] = v;
      }
    }
  } else {
    // ---------------- sim2 quarter (fp32-exact) ----------------
    const int id2 = id - 1024;
    const int b = id2 & 127, s = id2 >> 7;
    const int r0 = s * 128;
    const float* Fb = F + (size_t)b * (K * D);
    float* qs = (float*)smem;
    u64* wred = (u64*)(smem + 1024);
    const int sub = lane >> 4, cg = lane & 15;

    u64 e0 = p0[b * 8];
    #pragma unroll
    for (int i = 1; i < 8; ++i) e0 = umin64(e0, p0[b * 8 + i]);
    const int a0 = (int)(e0 & 0xffffffffu);

    qs[t] = Fb[(size_t)a0 * D + t];
    __syncthreads();

    u64 best = ~0ULL;
    #pragma unroll
    for (int pass = 0; pass < 8; ++pass) {
      const int r = r0 + pass * 16 + wave * 4 + sub;
      const float* fr = Fb + (size_t)r * D;
      float p = 0.f;
      #pragma unroll
      for (int q = 0; q < 2; ++q) {
        const int c = q * 128 + cg * 8;
        const float4 f0 = *(const float4*)(fr + c);
        const float4 f1 = *(const float4*)(fr + c + 4);
        const float4 q0 = *(const float4*)(qs + c);
        const float4 q1 = *(const float4*)(qs + c + 4);
        p += f0.x*q0.x + f0.y*q0.y + f0.z*q0.z + f0.w*q0.w
           + f1.x*q1.x + f1.y*q1.y + f1.z*q1.z + f1.w*q1.w;
      }
      p += __shfl_xor(p, 1, 64); p += __shfl_xor(p, 2, 64);
      p += __shfl_xor(p, 4, 64); p += __shfl_xor(p, 8, 64);
      if (cg == 0) {
        const float m = fmaxf(simbuf[(size_t)b * K + r], p);
        best = umin64(best, ((u64)f2o(m) << 32) | (unsigned int)r);
      }
    }
    best = umin64(best, __shfl_xor(best, 16, 64));
    best = umin64(best, __shfl_xor(best, 32, 64));
    if (lane == 0) wred[wave] = best;
    __syncthreads();
    if (t == 0)
      p1[b * 4 + s] =
          umin64(umin64(wred[0], wred[1]), umin64(wred[2], wred[3]));
  }
}

// ===== final: out = y + alpha*R*y + alpha/(1-alpha) * v * (v.y)  (NIT=1) =====
// anchor-column GEMVs read the bf16 F copy (half the traffic); anchors from p0/p1.
__global__ __launch_bounds__(256) void final_kernel(
    const float* __restrict__ F, const __bf16* __restrict__ Fbf,
    const float* __restrict__ Dgp, const u64* __restrict__ p0,
    const u64* __restrict__ p1, float* __restrict__ out)
{
  const int b = blockIdx.y;
  const int r0 = blockIdx.x * 128;
  const float* Fb = F + (size_t)b * (K * D);
  const __bf16* Fbb = Fbf + (size_t)b * (K * D);
  __shared__ __align__(16) float qa[D], qb[D];
  __shared__ float dinv_s[K], sqd_s[K];
  __shared__ float red[4];
  const int t = threadIdx.x;
  const int wave = t >> 6, lane = t & 63;
  const int sub = lane >> 4, cg = lane & 15;

  u64 e0 = p0[b * 8];
  #pragma unroll
  for (int i = 1; i < 8; ++i) e0 = umin64(e0, p0[b * 8 + i]);
  u64 e1 = p1[b * 4];
  #pragma unroll
  for (int i = 1; i < 4; ++i) e1 = umin64(e1, p1[b * 4 + i]);
  const int a0 = (int)(e0 & 0xffffffffu);
  const int a1 = (int)(e1 & 0xffffffffu);

  qa[t] = Fb[(size_t)a0 * D + t];
  qb[t] = Fb[(size_t)a1 * D + t];
  float dsum = 0.f;
  for (int k = t; k < K; k += 256) {
    const float d = Dgp[(size_t)b * K + k] + Dgp[(size_t)128 * K + (size_t)b * K + k];
    dinv_s[k] = 1.0f / sqrtf(d + EPSF);
    sqd_s[k] = sqrtf(d);
    dsum += d;
  }
  #pragma unroll
  for (int off = 32; off >= 1; off >>= 1) dsum += __shfl_down(dsum, off, 64);
  if (lane == 0) red[wave] = dsum;
  __syncthreads();
  const float vn = 1.0f / sqrtf(red[0] + red[1] + red[2] + red[3]);
  const float s0 = vn * sqd_s[a0], s1 = vn * sqd_s[a1];   // v[a0], v[a1]
  const float dia0 = dinv_s[a0], dia1 = dinv_s[a1];
  const float c99 = ALPHA / (1.0f - ALPHA);

  float2* ob = (float2*)(out + (size_t)b * K * 2);

  #pragma unroll
  for (int pass = 0; pass < 8; ++pass) {
    const int r = r0 + pass * 16 + wave * 4 + sub;
    const __bf16* fr = Fbb + (size_t)r * D;
    float pa = 0.f, pb = 0.f;
    #pragma unroll
    for (int q = 0; q < 2; ++q) {
      const int c = q * 128 + cg * 8;
      const uint4 wv = *(const uint4*)(fr + c);
      const float4 a0v = *(const float4*)(qa + c);
      const float4 a1v = *(const float4*)(qa + c + 4);
      const float4 b0v = *(const float4*)(qb + c);
      const float4 b1v = *(const float4*)(qb + c + 4);
      const float w0 = __uint_as_float(wv.x << 16);
      const float w1 = __uint_as_float(wv.x & 0xffff0000u);
      const float w2 = __uint_as_float(wv.y << 16);
      const float w3 = __uint_as_float(wv.y & 0xffff0000u);
      const float w4 = __uint_as_float(wv.z << 16);
      const float w5 = __uint_as_float(wv.z & 0xffff0000u);
      const float w6 = __uint_as_float(wv.w << 16);
      const float w7 = __uint_as_float(wv.w & 0xffff0000u);
      pa += w0*a0v.x + w1*a0v.y + w2*a0v.z + w3*a0v.w
          + w4*a1v.x + w5*a1v.y + w6*a1v.z + w7*a1v.w;
      pb += w0*b0v.x + w1*b0v.y + w2*b0v.z + w3*b0v.w
          + w4*b1v.x + w5*b1v.y + w6*b1v.z + w7*b1v.w;
    }
    pa += __shfl_xor(pa, 1, 64); pa += __shfl_xor(pa, 2, 64);
    pa += __shfl_xor(pa, 4, 64); pa += __shfl_xor(pa, 8, 64);
    pb += __shfl_xor(pb, 1, 64); pb += __shfl_xor(pb, 2, 64);
    pb += __shfl_xor(pb, 4, 64); pb += __shfl_xor(pb, 8, 64);
    if (cg == 0) {
      const float q0 = ((r == a0) ? 0.f : __expf(pa)) * dia0;
      const float q1 = ((r == a1) ? 0.f : __expf(pb)) * dia1;
      const float di = dinv_s[r];
      const float vr = vn * sqd_s[r];                      // v[r]
      const float w0n = ALPHA * (di * q0 - vr * s0);
      const float w1n = ALPHA * (di * q1 - vr * s1);
      float2 o;
      o.x = ((r == a0) ? 1.f : 0.f) + w0n + c99 * s0 * vr;
      o.y = ((r == a1) ? 1.f : 0.f) + w1n + c99 * s1 * vr;
      ob[r] = o;
    }
  }
}

// ==========================================================================
extern "C" void kernel_launch(void* const* d_in, const int* in_sizes, int n_in,
                              void* d_out, int out_size, void* d_ws, size_t ws_size,
                              hipStream_t stream) {
  const float* F = (const float*)d_in[0];   // [B,K,D]
  const float* Q = (const float*)d_in[1];   // [B,D]
  float* out = (float*)d_out;               // [B,K,2]
  const int B = in_sizes[1] / D;            // 128

  __bf16* Fbf = (__bf16*)d_ws;                           // B*K*D bf16 (33.5 MB)
  float* Dgp  = (float*)(Fbf + (size_t)B * K * D);       // 2*B*K (partial degrees)
  float* simb = Dgp + (size_t)2 * B * K;                 // B*K
  u64*   p0   = (u64*)(simb + (size_t)B * K);            // B*8
  u64*   p1   = p0 + (size_t)B * 8;                      // B*4

  sim1_kernel<<<dim3(8, B), 256, 0, stream>>>(F, Q, Fbf, simb, p0);
  fused_kernel<<<1536, 256, 0, stream>>>(F, Fbf, simb, p0, p1, Dgp);
  final_kernel<<<dim3(4, B), 256, 0, stream>>>(F, Fbf, Dgp, p0, p1, out);
}

// Round 11
// 136.542 us; speedup vs baseline: 2.4089x; 1.0695x over previous
//
#include <hip/hip_runtime.h>
#include <math.h>

static constexpr int K = 512;
static constexpr int D = 256;
static constexpr float ALPHA = 0.99f;
static constexpr float EPSF  = 2.2204460492503131e-16f;

typedef __bf16 bf16x8 __attribute__((ext_vector_type(8)));
typedef float floatx4 __attribute__((ext_vector_type(4)));
typedef unsigned long long u64;

// ordered-float encoding: monotone map float -> u32 (smaller float => smaller u32)
__device__ __forceinline__ unsigned int f2o(float f) {
  unsigned int u = __float_as_uint(f);
  return (u & 0x80000000u) ? ~u : (u | 0x80000000u);
}

__device__ __forceinline__ u64 umin64(u64 a, u64 b) { return a < b ? a : b; }

// ====== sim1: sim = F.q, per-block partial argmin; ALSO emits bf16 F ======
// grid (8, B): block covers 64 rows; partial best -> p0[b*8 + bx]
__global__ __launch_bounds__(256) void sim1_kernel(
    const float* __restrict__ F, const float* __restrict__ Q,
    __bf16* __restrict__ Fbf, float* __restrict__ simbuf, u64* __restrict__ p0)
{
  const int b = blockIdx.y;
  const int r0 = blockIdx.x * 64;
  const float* Fb = F + (size_t)b * (K * D);
  __bf16* Fbb = Fbf + (size_t)b * (K * D);
  __shared__ __align__(16) float qs[D];
  __shared__ u64 wred[4];
  const int t = threadIdx.x;
  const int wave = t >> 6, lane = t & 63;
  const int sub = lane >> 4, cg = lane & 15;
  qs[t] = Q[(size_t)b * D + t];
  __syncthreads();

  u64 best = ~0ULL;
  #pragma unroll
  for (int pass = 0; pass < 4; ++pass) {
    const int r = r0 + pass * 16 + wave * 4 + sub;
    const float* fr = Fb + (size_t)r * D;
    float p = 0.f;
    #pragma unroll
    for (int q = 0; q < 2; ++q) {
      const int c = q * 128 + cg * 8;
      const float4 f0 = *(const float4*)(fr + c);
      const float4 f1 = *(const float4*)(fr + c + 4);
      const float4 q0 = *(const float4*)(qs + c);
      const float4 q1 = *(const float4*)(qs + c + 4);
      p += f0.x*q0.x + f0.y*q0.y + f0.z*q0.z + f0.w*q0.w
         + f1.x*q1.x + f1.y*q1.y + f1.z*q1.z + f1.w*q1.w;
      bf16x8 h;
      h[0] = (__bf16)f0.x; h[1] = (__bf16)f0.y; h[2] = (__bf16)f0.z; h[3] = (__bf16)f0.w;
      h[4] = (__bf16)f1.x; h[5] = (__bf16)f1.y; h[6] = (__bf16)f1.z; h[7] = (__bf16)f1.w;
      *(bf16x8*)(Fbb + (size_t)r * D + c) = h;
    }
    p += __shfl_xor(p, 1, 64); p += __shfl_xor(p, 2, 64);
    p += __shfl_xor(p, 4, 64); p += __shfl_xor(p, 8, 64);
    if (cg == 0) {
      simbuf[(size_t)b * K + r] = p;
      best = umin64(best, ((u64)f2o(p) << 32) | (unsigned int)r);
    }
  }
  best = umin64(best, __shfl_xor(best, 16, 64));
  best = umin64(best, __shfl_xor(best, 32, 64));
  if (lane == 0) wred[wave] = best;
  __syncthreads();
  if (t == 0)
    p0[b * 8 + blockIdx.x] =
        umin64(umin64(wred[0], wred[1]), umin64(wred[2], wred[3]));
}

// ====== fused: blocks <1280 = lower-tri gram tiles (bf16 MFMA); rest = sim2 ======
// tile (ti,tj), ti>=tj: row-sums -> Dgp[tj][b][strip ti]; col-sums -> Dgp[ti][b][strip tj]
// (W symmetric: transpose-tile sums are bitwise identical, so 10 tiles replace 16)
__global__ __launch_bounds__(256) void fused_kernel(
    const float* __restrict__ F, const __bf16* __restrict__ Fbf,
    const float* __restrict__ simbuf, const u64* __restrict__ p0,
    u64* __restrict__ p1, float* __restrict__ Dgp)
{
  __shared__ __align__(16) unsigned char smem[36864];
  const int id = blockIdx.x;
  const int t = threadIdx.x;
  const int wave = t >> 6, lane = t & 63;
  const int quad = lane >> 4, l15 = lane & 15;

  if (id < 1280) {
    // ---------------- gram tile: 128 x 128 ----------------
    const int b = id & 127;
    const int tid = id >> 7;                 // 0..9
    static constexpr int TI[10] = {0,1,1,2,2,2,3,3,3,3};
    static constexpr int TJ[10] = {0,0,1,0,1,2,0,1,2,3};
    const int ti = TI[tid], tj = TJ[tid];
    const int r0 = ti * 128, c0 = tj * 128;
    const bool diag = (ti == tj);
    const __bf16* Fb = Fbf + (size_t)b * (K * D);
    __bf16 (*Asb)[72] = (__bf16(*)[72])smem;            // 128 x 72 bf16
    __bf16 (*Bsb)[72] = diag ? Asb : (__bf16(*)[72])(smem + 18432);
    const int srow = t >> 1, skh = (t & 1) * 32;

    floatx4 acc[2][8];
    #pragma unroll
    for (int i = 0; i < 2; ++i)
      #pragma unroll
      for (int j = 0; j < 8; ++j) acc[i][j] = (floatx4){0.f, 0.f, 0.f, 0.f};

    for (int kk = 0; kk < D; kk += 64) {
      __syncthreads();
      {
        const __bf16* sa = Fb + (size_t)(r0 + srow) * D + kk + skh;
        *(uint4*)&Asb[srow][skh +  0] = *(const uint4*)(sa +  0);
        *(uint4*)&Asb[srow][skh +  8] = *(const uint4*)(sa +  8);
        *(uint4*)&Asb[srow][skh + 16] = *(const uint4*)(sa + 16);
        *(uint4*)&Asb[srow][skh + 24] = *(const uint4*)(sa + 24);
        if (!diag) {
          const __bf16* sb = Fb + (size_t)(c0 + srow) * D + kk + skh;
          *(uint4*)&Bsb[srow][skh +  0] = *(const uint4*)(sb +  0);
          *(uint4*)&Bsb[srow][skh +  8] = *(const uint4*)(sb +  8);
          *(uint4*)&Bsb[srow][skh + 16] = *(const uint4*)(sb + 16);
          *(uint4*)&Bsb[srow][skh + 24] = *(const uint4*)(sb + 24);
        }
      }
      __syncthreads();
      #pragma unroll
      for (int k2 = 0; k2 < 64; k2 += 32) {
        bf16x8 af[2], bf[8];
        #pragma unroll
        for (int tm = 0; tm < 2; ++tm)
          af[tm] = *(bf16x8*)&Asb[wave * 32 + tm * 16 + l15][k2 + quad * 8];
        #pragma unroll
        for (int tn = 0; tn < 8; ++tn)
          bf[tn] = *(bf16x8*)&Bsb[tn * 16 + l15][k2 + quad * 8];
        #pragma unroll
        for (int tm = 0; tm < 2; ++tm)
          #pragma unroll
          for (int tn = 0; tn < 8; ++tn)
            acc[tm][tn] = __builtin_amdgcn_mfma_f32_16x16x32_bf16(af[tm], bf[tn], acc[tm][tn], 0, 0, 0);
      }
    }

    // epilogue: exp (+zero diag on diag tiles), row sums + col sums
    float rs[8] = {0.f};
    float cs[8] = {0.f};
    #pragma unroll
    for (int tm = 0; tm < 2; ++tm) {
      const int lrb = wave * 32 + tm * 16 + quad * 4;
      #pragma unroll
      for (int tn = 0; tn < 8; ++tn) {
        const int lc = tn * 16 + l15;
        #pragma unroll
        for (int r = 0; r < 4; ++r) {
          float wv = __expf(acc[tm][tn][r]);
          if (diag && (lrb + r) == lc) wv = 0.f;
          rs[tm * 4 + r] += wv;
          cs[tn] += wv;
        }
      }
    }
    // row sums -> slot tj
    #pragma unroll
    for (int s = 0; s < 8; ++s) {
      float v = rs[s];
      v += __shfl_xor(v, 1, 64); v += __shfl_xor(v, 2, 64);
      v += __shfl_xor(v, 4, 64); v += __shfl_xor(v, 8, 64);
      if (l15 == 0) {
        const int r = r0 + wave * 32 + (s >> 2) * 16 + quad * 4 + (s & 3);
        Dgp[(size_t)tj * (128 * K) + (size_t)b * K + r] = v;
      }
    }
    // col sums -> slot ti (off-diag tiles only)
    if (!diag) {
      #pragma unroll
      for (int tn = 0; tn < 8; ++tn) {
        cs[tn] += __shfl_xor(cs[tn], 16, 64);
        cs[tn] += __shfl_xor(cs[tn], 32, 64);
      }
      __syncthreads();                       // done with Asb/Bsb
      float* csum = (float*)smem;            // 4 x 128 floats
      if (lane < 16) {
        #pragma unroll
        for (int tn = 0; tn < 8; ++tn)
          csum[wave * 128 + tn * 16 + l15] = cs[tn];
      }
      __syncthreads();
      if (t < 128) {
        const float s = csum[t] + csum[128 + t] + csum[256 + t] + csum[384 + t];
        Dgp[(size_t)ti * (128 * K) + (size_t)b * K + c0 + t] = s;
      }
    }
  } else {
    // ---------------- sim2 quarter (fp32-exact) ----------------
    const int id2 = id - 1280;
    const int b = id2 & 127, s = id2 >> 7;
    const int r0 = s * 128;
    const float* Fb = F + (size_t)b * (K * D);
    float* qs = (float*)smem;
    u64* wred = (u64*)(smem + 1024);
    const int sub = lane >> 4, cg = lane & 15;

    u64 e0 = p0[b * 8];
    #pragma unroll
    for (int i = 1; i < 8; ++i) e0 = umin64(e0, p0[b * 8 + i]);
    const int a0 = (int)(e0 & 0xffffffffu);

    qs[t] = Fb[(size_t)a0 * D + t];
    __syncthreads();

    u64 best = ~0ULL;
    #pragma unroll
    for (int pass = 0; pass < 8; ++pass) {
      const int r = r0 + pass * 16 + wave * 4 + sub;
      const float* fr = Fb + (size_t)r * D;
      float p = 0.f;
      #pragma unroll
      for (int q = 0; q < 2; ++q) {
        const int c = q * 128 + cg * 8;
        const float4 f0 = *(const float4*)(fr + c);
        const float4 f1 = *(const float4*)(fr + c + 4);
        const float4 q0 = *(const float4*)(qs + c);
        const float4 q1 = *(const float4*)(qs + c + 4);
        p += f0.x*q0.x + f0.y*q0.y + f0.z*q0.z + f0.w*q0.w
           + f1.x*q1.x + f1.y*q1.y + f1.z*q1.z + f1.w*q1.w;
      }
      p += __shfl_xor(p, 1, 64); p += __shfl_xor(p, 2, 64);
      p += __shfl_xor(p, 4, 64); p += __shfl_xor(p, 8, 64);
      if (cg == 0) {
        const float m = fmaxf(simbuf[(size_t)b * K + r], p);
        best = umin64(best, ((u64)f2o(m) << 32) | (unsigned int)r);
      }
    }
    best = umin64(best, __shfl_xor(best, 16, 64));
    best = umin64(best, __shfl_xor(best, 32, 64));
    if (lane == 0) wred[wave] = best;
    __syncthreads();
    if (t == 0)
      p1[b * 4 + s] =
          umin64(umin64(wred[0], wred[1]), umin64(wred[2], wred[3]));
  }
}

// ===== final: out = y + alpha*R*y + alpha/(1-alpha) * v * (v.y)  (NIT=1) =====
// degrees = sum of 4 partial slots; anchor-column GEMVs read bf16 F.
__global__ __launch_bounds__(256) void final_kernel(
    const float* __restrict__ F, const __bf16* __restrict__ Fbf,
    const float* __restrict__ Dgp, const u64* __restrict__ p0,
    const u64* __restrict__ p1, float* __restrict__ out)
{
  const int b = blockIdx.y;
  const int r0 = blockIdx.x * 128;
  const float* Fb = F + (size_t)b * (K * D);
  const __bf16* Fbb = Fbf + (size_t)b * (K * D);
  __shared__ __align__(16) float qa[D], qb[D];
  __shared__ float dinv_s[K], sqd_s[K];
  __shared__ float red[4];
  const int t = threadIdx.x;
  const int wave = t >> 6, lane = t & 63;
  const int sub = lane >> 4, cg = lane & 15;

  u64 e0 = p0[b * 8];
  #pragma unroll
  for (int i = 1; i < 8; ++i) e0 = umin64(e0, p0[b * 8 + i]);
  u64 e1 = p1[b * 4];
  #pragma unroll
  for (int i = 1; i < 4; ++i) e1 = umin64(e1, p1[b * 4 + i]);
  const int a0 = (int)(e0 & 0xffffffffu);
  const int a1 = (int)(e1 & 0xffffffffu);

  qa[t] = Fb[(size_t)a0 * D + t];
  qb[t] = Fb[(size_t)a1 * D + t];
  float dsum = 0.f;
  for (int k = t; k < K; k += 256) {
    const size_t o = (size_t)b * K + k;
    const float d = Dgp[o] + Dgp[(size_t)128 * K + o]
                  + Dgp[(size_t)2 * 128 * K + o] + Dgp[(size_t)3 * 128 * K + o];
    dinv_s[k] = 1.0f / sqrtf(d + EPSF);
    sqd_s[k] = sqrtf(d);
    dsum += d;
  }
  #pragma unroll
  for (int off = 32; off >= 1; off >>= 1) dsum += __shfl_down(dsum, off, 64);
  if (lane == 0) red[wave] = dsum;
  __syncthreads();
  const float vn = 1.0f / sqrtf(red[0] + red[1] + red[2] + red[3]);
  const float s0 = vn * sqd_s[a0], s1 = vn * sqd_s[a1];   // v[a0], v[a1]
  const float dia0 = dinv_s[a0], dia1 = dinv_s[a1];
  const float c99 = ALPHA / (1.0f - ALPHA);

  float2* ob = (float2*)(out + (size_t)b * K * 2);

  #pragma unroll
  for (int pass = 0; pass < 8; ++pass) {
    const int r = r0 + pass * 16 + wave * 4 + sub;
    const __bf16* fr = Fbb + (size_t)r * D;
    float pa = 0.f, pb = 0.f;
    #pragma unroll
    for (int q = 0; q < 2; ++q) {
      const int c = q * 128 + cg * 8;
      const uint4 wv = *(const uint4*)(fr + c);
      const float4 a0v = *(const float4*)(qa + c);
      const float4 a1v = *(const float4*)(qa + c + 4);
      const float4 b0v = *(const float4*)(qb + c);
      const float4 b1v = *(const float4*)(qb + c + 4);
      const float w0 = __uint_as_float(wv.x << 16);
      const float w1 = __uint_as_float(wv.x & 0xffff0000u);
      const float w2 = __uint_as_float(wv.y << 16);
      const float w3 = __uint_as_float(wv.y & 0xffff0000u);
      const float w4 = __uint_as_float(wv.z << 16);
      const float w5 = __uint_as_float(wv.z & 0xffff0000u);
      const float w6 = __uint_as_float(wv.w << 16);
      const float w7 = __uint_as_float(wv.w & 0xffff0000u);
      pa += w0*a0v.x + w1*a0v.y + w2*a0v.z + w3*a0v.w
          + w4*a1v.x + w5*a1v.y + w6*a1v.z + w7*a1v.w;
      pb += w0*b0v.x + w1*b0v.y + w2*b0v.z + w3*b0v.w
          + w4*b1v.x + w5*b1v.y + w6*b1v.z + w7*b1v.w;
    }
    pa += __shfl_xor(pa, 1, 64); pa += __shfl_xor(pa, 2, 64);
    pa += __shfl_xor(pa, 4, 64); pa += __shfl_xor(pa, 8, 64);
    pb += __shfl_xor(pb, 1, 64); pb += __shfl_xor(pb, 2, 64);
    pb += __shfl_xor(pb, 4, 64); pb += __shfl_xor(pb, 8, 64);
    if (cg == 0) {
      const float q0 = ((r == a0) ? 0.f : __expf(pa)) * dia0;
      const float q1 = ((r == a1) ? 0.f : __expf(pb)) * dia1;
      const float di = dinv_s[r];
      const float vr = vn * sqd_s[r];                      // v[r]
      const float w0n = ALPHA * (di * q0 - vr * s0);
      const float w1n = ALPHA * (di * q1 - vr * s1);
      float2 o;
      o.x = ((r == a0) ? 1.f : 0.f) + w0n + c99 * s0 * vr;
      o.y = ((r == a1) ? 1.f : 0.f) + w1n + c99 * s1 * vr;
      ob[r] = o;
    }
  }
}

// ==========================================================================
extern "C" void kernel_launch(void* const* d_in, const int* in_sizes, int n_in,
                              void* d_out, int out_size, void* d_ws, size_t ws_size,
                              hipStream_t stream) {
  const float* F = (const float*)d_in[0];   // [B,K,D]
  const float* Q = (const float*)d_in[1];   // [B,D]
  float* out = (float*)d_out;               // [B,K,2]
  const int B = in_sizes[1] / D;            // 128

  __bf16* Fbf = (__bf16*)d_ws;                           // B*K*D bf16 (33.5 MB)
  float* Dgp  = (float*)(Fbf + (size_t)B * K * D);       // 4*B*K (partial degrees)
  float* simb = Dgp + (size_t)4 * B * K;                 // B*K
  u64*   p0   = (u64*)(simb + (size_t)B * K);            // B*8
  u64*   p1   = p0 + (size_t)B * 8;                      // B*4

  sim1_kernel<<<dim3(8, B), 256, 0, stream>>>(F, Q, Fbf, simb, p0);
  fused_kernel<<<1792, 256, 0, stream>>>(F, Fbf, simb, p0, p1, Dgp);
  final_kernel<<<dim3(4, B), 256, 0, stream>>>(F, Fbf, Dgp, p0, p1, out);
}